// Round 12
// baseline (883.304 us; speedup 1.0000x reference)
//
#include <hip/hip_runtime.h>
#include <hip/hip_bf16.h>

// DGL child-sum TreeLSTM, MFMA path, round 12 = round 11 with an LDS-free,
// barrier-free-inner-loop tail. r11: tail_kernel = 300us (36%), occupancy
// 1.4%, ~480 sequential {global->LDS->barrier->MFMA->barrier} iterations =
// pure latency chain. Fix: load every MFMA operand DIRECTLY from global
// (L2-warm) into fragment registers (bit-identical pattern to the LDS
// reads); stage3 all 4 waves work distinct hu-quarters (16 chunks, not
// 4q x 16); barriers only at stage boundaries (18/graph vs ~960).
// Facts: inputs fp32 (probed), x/par int32, out fp32, ws >= 152,961,088 B.

#define B_G     32
#define NPG     4095
#define NTOT    (B_G * NPG)
#define NCLS    104
#define VOCAB   20000
#define PAD_TOK 19999
#define KCAP    24
#define LB(d)   (32 * ((1 << (d)) - 1))   // level base in level-major order

typedef unsigned short u16;
typedef unsigned int   u32;
typedef __attribute__((ext_vector_type(8))) short bfrag8;  // 8 bf16
typedef __attribute__((ext_vector_type(4))) float ffrag4;  // 4 f32

__device__ __forceinline__ float bf2f(u16 v) {
    union { u32 u; float f; } x; x.u = ((u32)v) << 16; return x.f;
}
__device__ __forceinline__ u16 f2bf(float f) {
    union { __hip_bfloat16 h; u16 u; } c; c.h = __float2bfloat16(f); return c.u;
}
__device__ __forceinline__ float loadv(const void* b, int i, int isf32) {
    return isf32 ? ((const float*)b)[i] : bf2f(((const u16*)b)[i]);
}
__device__ __forceinline__ float sigf(float x) { return 1.f / (1.f + __expf(-x)); }

// --------------------------- dtype probe -----------------------------------
__global__ void probe_kernel(const void* emb, const void* Wiou, const void* Uiou,
                             const void* Ufw, const void* lw,
                             const int* x32, const int* par32, int* flags)
{
    if (threadIdx.x != 0 || blockIdx.x != 0) return;
    const void* ptrs[5] = { emb, Wiou, Uiou, Ufw, lw };
    for (int i = 0; i < 5; ++i) {
        const u16* p = (const u16*)ptrs[i];
        int big = 0;
        for (int k = 0; k < 128; ++k) {
            u32 e = (((u32)p[k]) << 16 >> 23) & 0xFF;
            if (e >= 129) ++big;
        }
        flags[i] = (big >= 4) ? 1 : 0;     // 1 => fp32
    }
    int zx = 1;
    for (int k = 1; k <= 15; k += 2) if (x32[k] != 0) zx = 0;
    flags[5] = zx;                         // 1 => x int64
    flags[6] = (par32[3] == 0 && par32[5] == 0) ? 1 : 0;  // 1 => par int64
}

// ------------------- prep: tokens + per-parent child lists ------------------
__global__ __launch_bounds__(256) void prep_kernel(
    const int* __restrict__ x, const int* __restrict__ par,
    int* __restrict__ tokLvl, int* __restrict__ cnt, int* __restrict__ bucket,
    const int* __restrict__ flags)
{
    int gid = blockIdx.x * 256 + threadIdx.x;
    if (gid >= NTOT) return;
    int g     = (int)((u32)gid / NPG);
    int local = gid - g * NPG;
    int v  = local + 1;
    int d  = 31 - __clz(v);
    int j  = local - ((1 << d) - 1);
    int tok = flags[5] ? x[2 * gid] : x[gid];
    if (tok < 0 || tok >= VOCAB) tok = PAD_TOK;
    tokLvl[LB(d) + (g << d) + j] = tok;
    if (local > 0) {
        int p  = flags[6] ? par[2 * gid] : par[gid];
        p = max(0, min(p, NTOT - 1));
        int pg = (int)((u32)p / NPG);
        int pl = p - pg * NPG;
        int pd = d - 1;
        int ps = LB(pd) + (pg << pd) + (pl - ((1 << pd) - 1));
        ps = max(0, min(ps, 65503));
        int slot = atomicAdd(&cnt[ps], 1);
        if (slot < KCAP) bucket[(size_t)ps * KCAP + slot] = (g << d) + j;
    }
}

// emb -> bf16 table, PAD row zeroed
__global__ __launch_bounds__(256) void embconv_kernel(
    const void* __restrict__ emb, u16* __restrict__ embb,
    const int* __restrict__ flags)
{
    int i8 = (blockIdx.x * 256 + threadIdx.x) * 8;
    if (i8 >= VOCAB * 256) return;
    u16 v[8];
    if ((i8 >> 8) == PAD_TOK) {
        #pragma unroll
        for (int s = 0; s < 8; ++s) v[s] = 0;
    } else if (flags[0]) {
        const float* e = (const float*)emb + i8;
        float4 a = *(const float4*)e;
        float4 b = *(const float4*)(e + 4);
        v[0]=f2bf(a.x); v[1]=f2bf(a.y); v[2]=f2bf(a.z); v[3]=f2bf(a.w);
        v[4]=f2bf(b.x); v[5]=f2bf(b.y); v[6]=f2bf(b.z); v[7]=f2bf(b.w);
    } else {
        *(uint4*)v = *(const uint4*)((const u16*)emb + i8);
    }
    *(uint4*)(embb + i8) = *(uint4*)v;
}

// combined [Wiou|Uiou] -> bf16, K-chunked wuc[c][768][32], c=0..15
__global__ __launch_bounds__(256) void wuc_kernel(
    const void* __restrict__ Wiou, const void* __restrict__ Uiou,
    u16* __restrict__ wuc, const int* __restrict__ flags)
{
    int idx = blockIdx.x * 256 + threadIdx.x;
    if (idx >= 16 * 768 * 32) return;
    int c   = idx / 24576;
    int rem = idx - c * 24576;
    int out = rem >> 5;
    int kk  = rem & 31;
    int k   = c * 32 + kk;
    float v = (k < 256) ? loadv(Wiou, out * 256 + k, flags[1])
                        : loadv(Uiou, out * 256 + (k - 256), flags[2]);
    wuc[idx] = f2bf(v);
}

// Ufw -> bf16, chunked ufc[c][256][32], c=0..7
__global__ __launch_bounds__(256) void ufc_kernel(
    const void* __restrict__ Ufw, u16* __restrict__ ufc,
    const int* __restrict__ flags)
{
    int idx = blockIdx.x * 256 + threadIdx.x;
    if (idx >= 8 * 256 * 32) return;
    int c   = idx >> 13;
    int rem = idx & 8191;
    int out = rem >> 5;
    int kk  = rem & 31;
    ufc[idx] = f2bf(loadv(Ufw, out * 256 + c * 32 + kk, flags[3]));
}

// GEMM1: fc = sigmoid(h_ch @ Ufw^T + b) * c_ch, IN-PLACE over cbuf. M=64.
__global__ __launch_bounds__(256, 3) void gemm1_kernel(
    const u16* __restrict__ hch, u16* cbuf,
    const u16* __restrict__ ufc, const void* __restrict__ ufb,
    const int* __restrict__ flags)
{
    __shared__ u16 As[64][40];
    __shared__ u16 Bs[256][40];
    const int t = threadIdx.x;
    const int w = t >> 6, lane = t & 63, quad = lane >> 4, l15 = lane & 15;
    const int m0 = blockIdx.x * 64;
    const int f_uf = flags[3];

    ffrag4 acc[4][4];
    #pragma unroll
    for (int i = 0; i < 4; ++i)
        #pragma unroll
        for (int j = 0; j < 4; ++j) acc[i][j] = (ffrag4)0.f;

    const int arow = t >> 2, aseg = t & 3;
    for (int c = 0; c < 8; ++c) {
        *(uint4*)&As[arow][aseg * 8] =
            *(const uint4*)(hch + (size_t)(m0 + arow) * 256 + c * 32 + aseg * 8);
        #pragma unroll
        for (int r16 = 0; r16 < 4; ++r16) {
            int row = r16 * 64 + arow;
            *(uint4*)&Bs[row][aseg * 8] =
                *(const uint4*)(ufc + ((size_t)c * 256 + row) * 32 + aseg * 8);
        }
        __syncthreads();
        bfrag8 a[4], b[4];
        #pragma unroll
        for (int mt = 0; mt < 4; ++mt) a[mt] = *(bfrag8*)&As[mt * 16 + l15][quad * 8];
        #pragma unroll
        for (int nt = 0; nt < 4; ++nt) b[nt] = *(bfrag8*)&Bs[w * 64 + nt * 16 + l15][quad * 8];
        #pragma unroll
        for (int mt = 0; mt < 4; ++mt)
            #pragma unroll
            for (int nt = 0; nt < 4; ++nt)
                acc[mt][nt] = __builtin_amdgcn_mfma_f32_16x16x32_bf16(a[mt], b[nt], acc[mt][nt], 0, 0, 0);
        __syncthreads();
    }

    #pragma unroll
    for (int nt = 0; nt < 4; ++nt) {
        int hu = w * 64 + nt * 16 + l15;
        float fb = loadv(ufb, hu, f_uf);
        #pragma unroll
        for (int mt = 0; mt < 4; ++mt) {
            #pragma unroll
            for (int r = 0; r < 4; ++r) {
                int node = m0 + mt * 16 + quad * 4 + r;
                size_t off = (size_t)node * 256 + hu;
                float f = sigf(acc[mt][nt][r] + fb);
                cbuf[off] = f2bf(f * bf2f(cbuf[off]));
            }
        }
    }
}

// agg: htild[p] = sum h_child, cagg[p] = sum fc_child. Coalesced.
__global__ __launch_bounds__(256) void agg_kernel(
    int NN, const u32* __restrict__ hch32, const u32* __restrict__ fcch32,
    const int* __restrict__ cnt_d, const int* __restrict__ bucket_d,
    u32* __restrict__ htild32, u32* __restrict__ cagg32)
{
    int pi  = blockIdx.x * 2 + (threadIdx.x >> 7);
    int col = threadIdx.x & 127;
    if (pi >= NN) return;
    int nc = min(cnt_d[pi], KCAP);
    float h0 = 0.f, h1 = 0.f, c0 = 0.f, c1 = 0.f;
    for (int ci = 0; ci < nc; ++ci) {
        int ch = bucket_d[(size_t)pi * KCAP + ci];
        u32 hv = hch32[(size_t)ch * 128 + col];
        u32 fv = fcch32[(size_t)ch * 128 + col];
        h0 += bf2f((u16)(hv & 0xffff)); h1 += bf2f((u16)(hv >> 16));
        c0 += bf2f((u16)(fv & 0xffff)); c1 += bf2f((u16)(fv >> 16));
    }
    htild32[(size_t)pi * 128 + col] = (u32)f2bf(h0) | ((u32)f2bf(h1) << 16);
    cagg32[(size_t)pi * 128 + col]  = (u32)f2bf(c0) | ((u32)f2bf(c1) << 16);
}

// GEMM2: IOU = [embb[x] | Htild] @ [Wiou|Uiou]^T + gates. M=128, N=192/block.
__global__ __launch_bounds__(256, 3) void gemm2_kernel(
    int nchunk, int NN,
    const int* __restrict__ tokLvl_d, const u16* __restrict__ embb,
    const u16* __restrict__ wuc, const void* __restrict__ biou,
    const u16* __restrict__ htild, const u16* __restrict__ cagg,
    u16* __restrict__ hdst, u16* __restrict__ cdst,
    const int* __restrict__ flags)
{
    __shared__ u16 As[128][40];
    __shared__ u16 Bs[192][40];
    __shared__ int toks[128];
    const int t = threadIdx.x;
    const int w = t >> 6, lane = t & 63, quad = lane >> 4, l15 = lane & 15;
    const int m0 = blockIdx.x * 128;
    const int q  = blockIdx.y;
    const int f_b = flags[1];

    if (t < 128) toks[t] = tokLvl_d[m0 + t];
    __syncthreads();

    ffrag4 acc[8][3];
    #pragma unroll
    for (int i = 0; i < 8; ++i)
        #pragma unroll
        for (int j = 0; j < 3; ++j) acc[i][j] = (ffrag4)0.f;

    const int arow = t >> 1, ac0 = (t & 1) * 16;
    const int brow = t >> 2, bseg = t & 3;
    for (int c = 0; c < nchunk; ++c) {
        if (c < 8) {
            const u16* e = embb + (size_t)toks[arow] * 256 + c * 32 + ac0;
            *(uint4*)&As[arow][ac0]     = *(const uint4*)e;
            *(uint4*)&As[arow][ac0 + 8] = *(const uint4*)(e + 8);
        } else {
            const u16* hsrc = htild + (size_t)(m0 + arow) * 256 + (c - 8) * 32 + ac0;
            *(uint4*)&As[arow][ac0]     = *(const uint4*)hsrc;
            *(uint4*)&As[arow][ac0 + 8] = *(const uint4*)(hsrc + 8);
        }
        #pragma unroll
        for (int g = 0; g < 3; ++g) {
            *(uint4*)&Bs[g * 64 + brow][bseg * 8] =
                *(const uint4*)(wuc + ((size_t)c * 768 + g * 256 + q * 64 + brow) * 32 + bseg * 8);
        }
        __syncthreads();
        bfrag8 a[8], b[3];
        #pragma unroll
        for (int mt = 0; mt < 8; ++mt) a[mt] = *(bfrag8*)&As[mt * 16 + l15][quad * 8];
        #pragma unroll
        for (int g = 0; g < 3; ++g) b[g] = *(bfrag8*)&Bs[g * 64 + w * 16 + l15][quad * 8];
        #pragma unroll
        for (int mt = 0; mt < 8; ++mt)
            #pragma unroll
            for (int g = 0; g < 3; ++g)
                acc[mt][g] = __builtin_amdgcn_mfma_f32_16x16x32_bf16(a[mt], b[g], acc[mt][g], 0, 0, 0);
        __syncthreads();
    }

    const int hu = q * 64 + w * 16 + l15;
    const float bi = loadv(biou, hu,       f_b);
    const float bo = loadv(biou, 256 + hu, f_b);
    const float bu = loadv(biou, 512 + hu, f_b);
    #pragma unroll
    for (int mt = 0; mt < 8; ++mt) {
        #pragma unroll
        for (int r = 0; r < 4; ++r) {
            int node = m0 + mt * 16 + quad * 4 + r;
            if (node < NN) {
                size_t off = (size_t)node * 256 + hu;
                float iv = acc[mt][0][r] + bi;
                float ov = acc[mt][1][r] + bo;
                float uv = acc[mt][2][r] + bu;
                float cg = cagg ? bf2f(cagg[off]) : 0.f;
                float cn = sigf(iv) * tanhf(uv) + cg;
                float hn = sigf(ov) * tanhf(cn);
                hdst[off] = f2bf(hn);
                cdst[off] = f2bf(cn);
            }
        }
    }
}

// tail: levels d=5..0 + final linear, ONE block per graph. LDS-FREE GEMMs:
// all MFMA operands loaded directly from global (L2-warm) into fragment
// registers; barriers only at stage boundaries. htild/cagg rows private
// per graph (row = g*32 + pi).
__global__ __launch_bounds__(256) void tail_kernel(
    const int* __restrict__ tokLvl, const u16* __restrict__ embb,
    const u16* __restrict__ wuc, const void* __restrict__ biou,
    const u16* __restrict__ ufc, const void* __restrict__ ufb,
    u16* hA, u16* cA, u16* hB, u16* cB,
    u16* htild, u16* cagg,
    const int* __restrict__ cnt, const int* __restrict__ bucket,
    const void* __restrict__ lw, const void* __restrict__ lb,
    float* __restrict__ out, const int* __restrict__ flags)
{
    __shared__ float hr[256];
    const int t = threadIdx.x;
    const int g = blockIdx.x;
    const int w = t >> 6, lane = t & 63, quad = lane >> 4, l15 = lane & 15;
    const int f_uf = flags[3], f_b = flags[1], f_lw = flags[4];
    const int pr0 = g * 32;                // private htild/cagg row base

    for (int d = 5; d >= 0; --d) {
        const int cl  = d + 1;
        const int ncr = 1 << cl;       // children rows this graph (<=64)
        const int np  = 1 << d;        // parent rows this graph (<=32)
        const int cb0 = g << cl;
        const int p0  = g << d;
        u16* hch  = (cl & 1) ? hA : hB;
        u16* cch  = (cl & 1) ? cA : cB;
        u16* hdst = (d & 1) ? hA : hB;
        u16* cdst = (d & 1) ? cA : cB;

        // ---- stage 1: fc in place, M=64 (masked), direct-frag loads ----
        {
            ffrag4 acc[4][4];
            #pragma unroll
            for (int i = 0; i < 4; ++i)
                #pragma unroll
                for (int j = 0; j < 4; ++j) acc[i][j] = (ffrag4)0.f;
            #pragma unroll
            for (int c = 0; c < 8; ++c) {
                bfrag8 a[4], b[4];
                #pragma unroll
                for (int mt = 0; mt < 4; ++mt)
                    a[mt] = *(const bfrag8*)(hch + (size_t)(cb0 + mt * 16 + l15) * 256 + c * 32 + quad * 8);
                #pragma unroll
                for (int nt = 0; nt < 4; ++nt)
                    b[nt] = *(const bfrag8*)(ufc + ((size_t)c * 256 + w * 64 + nt * 16 + l15) * 32 + quad * 8);
                #pragma unroll
                for (int mt = 0; mt < 4; ++mt)
                    #pragma unroll
                    for (int nt = 0; nt < 4; ++nt)
                        acc[mt][nt] = __builtin_amdgcn_mfma_f32_16x16x32_bf16(a[mt], b[nt], acc[mt][nt], 0, 0, 0);
            }
            #pragma unroll
            for (int nt = 0; nt < 4; ++nt) {
                int hu = w * 64 + nt * 16 + l15;
                float fb = loadv(ufb, hu, f_uf);
                #pragma unroll
                for (int mt = 0; mt < 4; ++mt) {
                    #pragma unroll
                    for (int r = 0; r < 4; ++r) {
                        int j = mt * 16 + quad * 4 + r;
                        if (j < ncr) {
                            size_t off = (size_t)(cb0 + j) * 256 + hu;
                            float f = sigf(acc[mt][nt][r] + fb);
                            cch[off] = f2bf(f * bf2f(cch[off]));
                        }
                    }
                }
            }
        }
        __syncthreads();

        // ---- stage 2: agg per parent (PRIVATE rows pr0+pi) ----
        {
            const int col = t & 127;
            const u32* h32 = (const u32*)hch;
            const u32* f32p = (const u32*)cch;
            for (int pi = t >> 7; pi < np; pi += 2) {
                int nc = min(cnt[LB(d) + p0 + pi], KCAP);
                const int* bk = bucket + (size_t)(LB(d) + p0 + pi) * KCAP;
                float h0 = 0.f, h1 = 0.f, c0 = 0.f, c1 = 0.f;
                for (int ci = 0; ci < nc; ++ci) {
                    int ch = bk[ci];
                    u32 hv = h32[(size_t)ch * 128 + col];
                    u32 fv = f32p[(size_t)ch * 128 + col];
                    h0 += bf2f((u16)(hv & 0xffff)); h1 += bf2f((u16)(hv >> 16));
                    c0 += bf2f((u16)(fv & 0xffff)); c1 += bf2f((u16)(fv >> 16));
                }
                ((u32*)htild)[(size_t)(pr0 + pi) * 128 + col] = (u32)f2bf(h0) | ((u32)f2bf(h1) << 16);
                ((u32*)cagg)[(size_t)(pr0 + pi) * 128 + col]  = (u32)f2bf(c0) | ((u32)f2bf(c1) << 16);
            }
        }
        __syncthreads();

        // ---- stage 3: M=32 (masked), wave w owns hu-quarter w, 16 chunks ----
        {
            ffrag4 acc[2][12];
            #pragma unroll
            for (int i = 0; i < 2; ++i)
                #pragma unroll
                for (int j = 0; j < 12; ++j) acc[i][j] = (ffrag4)0.f;
            #pragma unroll
            for (int c = 0; c < 16; ++c) {
                bfrag8 a[2], b[12];
                #pragma unroll
                for (int mt = 0; mt < 2; ++mt) {
                    int row = mt * 16 + l15;
                    if (c < 8) {
                        int tok = tokLvl[LB(d) + p0 + row];   // rows>=np read stale tokens; masked at store
                        a[mt] = *(const bfrag8*)(embb + (size_t)tok * 256 + c * 32 + quad * 8);
                    } else {
                        a[mt] = *(const bfrag8*)(htild + (size_t)(pr0 + row) * 256 + (c - 8) * 32 + quad * 8);
                    }
                }
                #pragma unroll
                for (int g3 = 0; g3 < 3; ++g3)
                    #pragma unroll
                    for (int st = 0; st < 4; ++st)
                        b[g3 * 4 + st] = *(const bfrag8*)(wuc + ((size_t)c * 768 + g3 * 256 + w * 64 + st * 16 + l15) * 32 + quad * 8);
                #pragma unroll
                for (int mt = 0; mt < 2; ++mt)
                    #pragma unroll
                    for (int nt = 0; nt < 12; ++nt)
                        acc[mt][nt] = __builtin_amdgcn_mfma_f32_16x16x32_bf16(a[mt], b[nt], acc[mt][nt], 0, 0, 0);
            }
            #pragma unroll
            for (int st = 0; st < 4; ++st) {
                int hu = w * 64 + st * 16 + l15;
                float bi = loadv(biou, hu,       f_b);
                float bo = loadv(biou, 256 + hu, f_b);
                float bu = loadv(biou, 512 + hu, f_b);
                #pragma unroll
                for (int mt = 0; mt < 2; ++mt) {
                    #pragma unroll
                    for (int r = 0; r < 4; ++r) {
                        int j = mt * 16 + quad * 4 + r;
                        if (j < np) {
                            size_t off = (size_t)(p0 + j) * 256 + hu;
                            float iv = acc[mt][0 * 4 + st][r] + bi;
                            float ov = acc[mt][1 * 4 + st][r] + bo;
                            float uv = acc[mt][2 * 4 + st][r] + bu;
                            float cg = bf2f(cagg[(size_t)(pr0 + j) * 256 + hu]);
                            float cn = sigf(iv) * tanhf(uv) + cg;
                            float hn = sigf(ov) * tanhf(cn);
                            hdst[off] = f2bf(hn);
                            cdst[off] = f2bf(cn);
                        }
                    }
                }
            }
        }
        __syncthreads();
    }

    // ---- final linear: out[g,:] = h_root @ lw^T + lb ----
    hr[t] = bf2f(hB[(size_t)g * 256 + t]);
    __syncthreads();
    if (t < NCLS) {
        float acc = 0.f;
        for (int k = 0; k < 256; ++k)
            acc += loadv(lw, t * 256 + k, f_lw) * hr[k];
        acc += loadv(lb, t, f_lw);
        out[(size_t)g * NCLS + t] = acc;
    }
}

__global__ void fill_kernel(float* out, int n, float v) {
    int i = blockIdx.x * 256 + threadIdx.x;
    if (i < n) out[i] = v;
}

// ============================ launcher =====================================
extern "C" void kernel_launch(void* const* d_in, const int* in_sizes, int n_in,
                              void* d_out, int out_size, void* d_ws, size_t ws_size,
                              hipStream_t stream)
{
    float* out = (float*)d_out;

    static const int exp_sizes[10] = {131040, 131040, 5120000, 196608, 196608,
                                      768, 65536, 256, 26624, 104};
    bool shapes_ok = (n_in == 10) && (out_size == B_G * NCLS);
    for (int i = 0; i < 10 && shapes_ok; ++i)
        if (in_sizes[i] != exp_sizes[i]) shapes_ok = false;
    if (!shapes_ok) {
        fill_kernel<<<(out_size + 255) / 256, 256, 0, stream>>>(out, out_size, 2.0f);
        return;
    }

    const int* x     = (const int*)d_in[0];
    const int* par   = (const int*)d_in[1];
    const void* emb  = d_in[2];
    const void* Wiou = d_in[3];
    const void* Uiou = d_in[4];
    const void* biou = d_in[5];
    const void* Ufw  = d_in[6];
    const void* Ufb  = d_in[7];
    const void* lw   = d_in[8];
    const void* lb   = d_in[9];

    // -------- workspace layout (byte offsets); total 152,453,184 B --------
    char* W = (char*)d_ws;
    u16* hA     = (u16*)(W + 0);              // bf16 [65536][256] odd levels
    u16* hB     = (u16*)(W + 33554432);       // bf16 [32768][256] even levels
    u16* cA     = (u16*)(W + 50331648);       // bf16 [65536][256] (fc in-place)
    u16* cB     = (u16*)(W + 83886080);       // bf16 [32768][256]
    u16* htild  = (u16*)(W + 100663296);      // bf16 [32768][256]
    u16* cagg   = (u16*)(W + 117440512);      // bf16 [32768][256]
    u16* WUc    = (u16*)(W + 134217728);      // bf16 [16][768][32]
    u16* Ufc    = (u16*)(W + 135004160);      // bf16 [8][256][32]
    int* tokLvl = (int*)(W + 135135232);      // int  [131072]
    int* cnt    = (int*)(W + 135659520);      // int  [65536]
    int* bucket = (int*)(W + 135921664);      // int  [65536*KCAP]
    u16* embb   = (u16*)(W + 142213120);      // bf16 [20000][256]
    int* flags  = (int*)(W + 152453120);      // int  [16]
    const size_t NEED = 152453184;            // <= 152,961,088 known-fit (r7)
    if (ws_size < NEED) {
        fill_kernel<<<(out_size + 255) / 256, 256, 0, stream>>>(out, out_size, 1.0f);
        return;
    }

    hipMemsetAsync(cnt, 0, 65536 * sizeof(int), stream);
    probe_kernel<<<1, 1, 0, stream>>>(emb, Wiou, Uiou, Ufw, lw, x, par, flags);
    prep_kernel<<<(NTOT + 255) / 256, 256, 0, stream>>>(x, par, tokLvl, cnt, bucket, flags);
    embconv_kernel<<<2500, 256, 0, stream>>>(emb, embb, flags);
    wuc_kernel<<<1536, 256, 0, stream>>>(Wiou, Uiou, WUc, flags);
    ufc_kernel<<<256, 256, 0, stream>>>(Ufw, Ufc, flags);

    // leaves d=11 (odd parity -> hA/cA), K=256
    gemm2_kernel<<<dim3(512, 4), 256, 0, stream>>>(
        8, 65536, tokLvl + LB(11), embb, WUc, biou,
        nullptr, nullptr, hA, cA, flags);

    for (int d = 10; d >= 6; --d) {
        const int cl = d + 1;
        const int NC = B_G << cl;
        const int NN = B_G << d;
        const u16* hch = (cl & 1) ? hA : hB;
        u16*       cch = (cl & 1) ? cA : cB;   // becomes fc in-place
        u16* hdst = (d & 1) ? hA : hB;
        u16* cdst = (d & 1) ? cA : cB;
        gemm1_kernel<<<NC / 64, 256, 0, stream>>>(hch, cch, Ufc, Ufb, flags);
        agg_kernel<<<(NN + 1) / 2, 256, 0, stream>>>(
            NN, (const u32*)hch, (const u32*)cch,
            cnt + LB(d), bucket + (size_t)LB(d) * KCAP,
            (u32*)htild, (u32*)cagg);
        gemm2_kernel<<<dim3((NN + 127) / 128, 4), 256, 0, stream>>>(
            16, NN, tokLvl + LB(d), embb, WUc, biou,
            htild, cagg, hdst, cdst, flags);
    }

    // levels d=5..0 + final linear: one block per graph
    tail_kernel<<<B_G, 256, 0, stream>>>(
        tokLvl, embb, WUc, biou, Ufc, Ufb,
        hA, cA, hB, cB, htild, cagg, cnt, bucket,
        lw, lb, out, flags);
}

// Round 13
// 858.703 us; speedup vs baseline: 1.0286x; 1.0286x over previous
//
#include <hip/hip_runtime.h>
#include <hip/hip_bf16.h>

// DGL child-sum TreeLSTM, MFMA path, round 13.
// Tail (d=5..0 + final linear) is now LDS/REGISTER-RESIDENT, one block/graph:
//   - child h lives in LDS hs[64][264]; htild in hts[32][264]
//   - c lives in REGISTERS across levels (stage3 epilogue (row,hu) mapping ==
//     next stage1 fc mapping); fc overwrites dead child-h rows in LDS;
//     cagg gathered into registers. ZERO global writes in the tail.
//   - 4 barriers/level (24 total) vs r11's ~960 / r12's global round trips.
// r12 post-mortem: direct-global tail = 370us; state bounced through L2
// (WRITE_SIZE 26.5MB) with vmcnt(0) drains at 1.4% occupancy.
// Facts: inputs fp32 (probed), x/par int32, out fp32, ws >= 152,961,088 B.

#define B_G     32
#define NPG     4095
#define NTOT    (B_G * NPG)
#define NCLS    104
#define VOCAB   20000
#define PAD_TOK 19999
#define KCAP    24
#define LB(d)   (32 * ((1 << (d)) - 1))   // level base in level-major order

typedef unsigned short u16;
typedef unsigned int   u32;
typedef __attribute__((ext_vector_type(8))) short bfrag8;  // 8 bf16
typedef __attribute__((ext_vector_type(4))) float ffrag4;  // 4 f32

__device__ __forceinline__ float bf2f(u16 v) {
    union { u32 u; float f; } x; x.u = ((u32)v) << 16; return x.f;
}
__device__ __forceinline__ u16 f2bf(float f) {
    union { __hip_bfloat16 h; u16 u; } c; c.h = __float2bfloat16(f); return c.u;
}
__device__ __forceinline__ float loadv(const void* b, int i, int isf32) {
    return isf32 ? ((const float*)b)[i] : bf2f(((const u16*)b)[i]);
}
__device__ __forceinline__ float sigf(float x) { return 1.f / (1.f + __expf(-x)); }

// --------------------------- dtype probe -----------------------------------
__global__ void probe_kernel(const void* emb, const void* Wiou, const void* Uiou,
                             const void* Ufw, const void* lw,
                             const int* x32, const int* par32, int* flags)
{
    if (threadIdx.x != 0 || blockIdx.x != 0) return;
    const void* ptrs[5] = { emb, Wiou, Uiou, Ufw, lw };
    for (int i = 0; i < 5; ++i) {
        const u16* p = (const u16*)ptrs[i];
        int big = 0;
        for (int k = 0; k < 128; ++k) {
            u32 e = (((u32)p[k]) << 16 >> 23) & 0xFF;
            if (e >= 129) ++big;
        }
        flags[i] = (big >= 4) ? 1 : 0;     // 1 => fp32
    }
    int zx = 1;
    for (int k = 1; k <= 15; k += 2) if (x32[k] != 0) zx = 0;
    flags[5] = zx;                         // 1 => x int64
    flags[6] = (par32[3] == 0 && par32[5] == 0) ? 1 : 0;  // 1 => par int64
}

// ------------------- prep: tokens + per-parent child lists ------------------
__global__ __launch_bounds__(256) void prep_kernel(
    const int* __restrict__ x, const int* __restrict__ par,
    int* __restrict__ tokLvl, int* __restrict__ cnt, int* __restrict__ bucket,
    const int* __restrict__ flags)
{
    int gid = blockIdx.x * 256 + threadIdx.x;
    if (gid >= NTOT) return;
    int g     = (int)((u32)gid / NPG);
    int local = gid - g * NPG;
    int v  = local + 1;
    int d  = 31 - __clz(v);
    int j  = local - ((1 << d) - 1);
    int tok = flags[5] ? x[2 * gid] : x[gid];
    if (tok < 0 || tok >= VOCAB) tok = PAD_TOK;
    tokLvl[LB(d) + (g << d) + j] = tok;
    if (local > 0) {
        int p  = flags[6] ? par[2 * gid] : par[gid];
        p = max(0, min(p, NTOT - 1));
        int pg = (int)((u32)p / NPG);
        int pl = p - pg * NPG;
        int pd = d - 1;
        int ps = LB(pd) + (pg << pd) + (pl - ((1 << pd) - 1));
        ps = max(0, min(ps, 65503));
        int slot = atomicAdd(&cnt[ps], 1);
        if (slot < KCAP) bucket[(size_t)ps * KCAP + slot] = (g << d) + j;
    }
}

// emb -> bf16 table, PAD row zeroed
__global__ __launch_bounds__(256) void embconv_kernel(
    const void* __restrict__ emb, u16* __restrict__ embb,
    const int* __restrict__ flags)
{
    int i8 = (blockIdx.x * 256 + threadIdx.x) * 8;
    if (i8 >= VOCAB * 256) return;
    u16 v[8];
    if ((i8 >> 8) == PAD_TOK) {
        #pragma unroll
        for (int s = 0; s < 8; ++s) v[s] = 0;
    } else if (flags[0]) {
        const float* e = (const float*)emb + i8;
        float4 a = *(const float4*)e;
        float4 b = *(const float4*)(e + 4);
        v[0]=f2bf(a.x); v[1]=f2bf(a.y); v[2]=f2bf(a.z); v[3]=f2bf(a.w);
        v[4]=f2bf(b.x); v[5]=f2bf(b.y); v[6]=f2bf(b.z); v[7]=f2bf(b.w);
    } else {
        *(uint4*)v = *(const uint4*)((const u16*)emb + i8);
    }
    *(uint4*)(embb + i8) = *(uint4*)v;
}

// combined [Wiou|Uiou] -> bf16, K-chunked wuc[c][768][32], c=0..15
__global__ __launch_bounds__(256) void wuc_kernel(
    const void* __restrict__ Wiou, const void* __restrict__ Uiou,
    u16* __restrict__ wuc, const int* __restrict__ flags)
{
    int idx = blockIdx.x * 256 + threadIdx.x;
    if (idx >= 16 * 768 * 32) return;
    int c   = idx / 24576;
    int rem = idx - c * 24576;
    int out = rem >> 5;
    int kk  = rem & 31;
    int k   = c * 32 + kk;
    float v = (k < 256) ? loadv(Wiou, out * 256 + k, flags[1])
                        : loadv(Uiou, out * 256 + (k - 256), flags[2]);
    wuc[idx] = f2bf(v);
}

// Ufw -> bf16, chunked ufc[c][256][32], c=0..7
__global__ __launch_bounds__(256) void ufc_kernel(
    const void* __restrict__ Ufw, u16* __restrict__ ufc,
    const int* __restrict__ flags)
{
    int idx = blockIdx.x * 256 + threadIdx.x;
    if (idx >= 8 * 256 * 32) return;
    int c   = idx >> 13;
    int rem = idx & 8191;
    int out = rem >> 5;
    int kk  = rem & 31;
    ufc[idx] = f2bf(loadv(Ufw, out * 256 + c * 32 + kk, flags[3]));
}

// GEMM1: fc = sigmoid(h_ch @ Ufw^T + b) * c_ch, IN-PLACE over cbuf. M=64.
__global__ __launch_bounds__(256, 3) void gemm1_kernel(
    const u16* __restrict__ hch, u16* cbuf,
    const u16* __restrict__ ufc, const void* __restrict__ ufb,
    const int* __restrict__ flags)
{
    __shared__ u16 As[64][40];
    __shared__ u16 Bs[256][40];
    const int t = threadIdx.x;
    const int w = t >> 6, lane = t & 63, quad = lane >> 4, l15 = lane & 15;
    const int m0 = blockIdx.x * 64;
    const int f_uf = flags[3];

    ffrag4 acc[4][4];
    #pragma unroll
    for (int i = 0; i < 4; ++i)
        #pragma unroll
        for (int j = 0; j < 4; ++j) acc[i][j] = (ffrag4)0.f;

    const int arow = t >> 2, aseg = t & 3;
    for (int c = 0; c < 8; ++c) {
        *(uint4*)&As[arow][aseg * 8] =
            *(const uint4*)(hch + (size_t)(m0 + arow) * 256 + c * 32 + aseg * 8);
        #pragma unroll
        for (int r16 = 0; r16 < 4; ++r16) {
            int row = r16 * 64 + arow;
            *(uint4*)&Bs[row][aseg * 8] =
                *(const uint4*)(ufc + ((size_t)c * 256 + row) * 32 + aseg * 8);
        }
        __syncthreads();
        bfrag8 a[4], b[4];
        #pragma unroll
        for (int mt = 0; mt < 4; ++mt) a[mt] = *(bfrag8*)&As[mt * 16 + l15][quad * 8];
        #pragma unroll
        for (int nt = 0; nt < 4; ++nt) b[nt] = *(bfrag8*)&Bs[w * 64 + nt * 16 + l15][quad * 8];
        #pragma unroll
        for (int mt = 0; mt < 4; ++mt)
            #pragma unroll
            for (int nt = 0; nt < 4; ++nt)
                acc[mt][nt] = __builtin_amdgcn_mfma_f32_16x16x32_bf16(a[mt], b[nt], acc[mt][nt], 0, 0, 0);
        __syncthreads();
    }

    #pragma unroll
    for (int nt = 0; nt < 4; ++nt) {
        int hu = w * 64 + nt * 16 + l15;
        float fb = loadv(ufb, hu, f_uf);
        #pragma unroll
        for (int mt = 0; mt < 4; ++mt) {
            #pragma unroll
            for (int r = 0; r < 4; ++r) {
                int node = m0 + mt * 16 + quad * 4 + r;
                size_t off = (size_t)node * 256 + hu;
                float f = sigf(acc[mt][nt][r] + fb);
                cbuf[off] = f2bf(f * bf2f(cbuf[off]));
            }
        }
    }
}

// agg: htild[p] = sum h_child, cagg[p] = sum fc_child. Coalesced.
__global__ __launch_bounds__(256) void agg_kernel(
    int NN, const u32* __restrict__ hch32, const u32* __restrict__ fcch32,
    const int* __restrict__ cnt_d, const int* __restrict__ bucket_d,
    u32* __restrict__ htild32, u32* __restrict__ cagg32)
{
    int pi  = blockIdx.x * 2 + (threadIdx.x >> 7);
    int col = threadIdx.x & 127;
    if (pi >= NN) return;
    int nc = min(cnt_d[pi], KCAP);
    float h0 = 0.f, h1 = 0.f, c0 = 0.f, c1 = 0.f;
    for (int ci = 0; ci < nc; ++ci) {
        int ch = bucket_d[(size_t)pi * KCAP + ci];
        u32 hv = hch32[(size_t)ch * 128 + col];
        u32 fv = fcch32[(size_t)ch * 128 + col];
        h0 += bf2f((u16)(hv & 0xffff)); h1 += bf2f((u16)(hv >> 16));
        c0 += bf2f((u16)(fv & 0xffff)); c1 += bf2f((u16)(fv >> 16));
    }
    htild32[(size_t)pi * 128 + col] = (u32)f2bf(h0) | ((u32)f2bf(h1) << 16);
    cagg32[(size_t)pi * 128 + col]  = (u32)f2bf(c0) | ((u32)f2bf(c1) << 16);
}

// GEMM2: IOU = [embb[x] | Htild] @ [Wiou|Uiou]^T + gates. M=128, N=192/block.
__global__ __launch_bounds__(256, 3) void gemm2_kernel(
    int nchunk, int NN,
    const int* __restrict__ tokLvl_d, const u16* __restrict__ embb,
    const u16* __restrict__ wuc, const void* __restrict__ biou,
    const u16* __restrict__ htild, const u16* __restrict__ cagg,
    u16* __restrict__ hdst, u16* __restrict__ cdst,
    const int* __restrict__ flags)
{
    __shared__ u16 As[128][40];
    __shared__ u16 Bs[192][40];
    __shared__ int toks[128];
    const int t = threadIdx.x;
    const int w = t >> 6, lane = t & 63, quad = lane >> 4, l15 = lane & 15;
    const int m0 = blockIdx.x * 128;
    const int q  = blockIdx.y;
    const int f_b = flags[1];

    if (t < 128) toks[t] = tokLvl_d[m0 + t];
    __syncthreads();

    ffrag4 acc[8][3];
    #pragma unroll
    for (int i = 0; i < 8; ++i)
        #pragma unroll
        for (int j = 0; j < 3; ++j) acc[i][j] = (ffrag4)0.f;

    const int arow = t >> 1, ac0 = (t & 1) * 16;
    const int brow = t >> 2, bseg = t & 3;
    for (int c = 0; c < nchunk; ++c) {
        if (c < 8) {
            const u16* e = embb + (size_t)toks[arow] * 256 + c * 32 + ac0;
            *(uint4*)&As[arow][ac0]     = *(const uint4*)e;
            *(uint4*)&As[arow][ac0 + 8] = *(const uint4*)(e + 8);
        } else {
            const u16* hsrc = htild + (size_t)(m0 + arow) * 256 + (c - 8) * 32 + ac0;
            *(uint4*)&As[arow][ac0]     = *(const uint4*)hsrc;
            *(uint4*)&As[arow][ac0 + 8] = *(const uint4*)(hsrc + 8);
        }
        #pragma unroll
        for (int g = 0; g < 3; ++g) {
            *(uint4*)&Bs[g * 64 + brow][bseg * 8] =
                *(const uint4*)(wuc + ((size_t)c * 768 + g * 256 + q * 64 + brow) * 32 + bseg * 8);
        }
        __syncthreads();
        bfrag8 a[8], b[3];
        #pragma unroll
        for (int mt = 0; mt < 8; ++mt) a[mt] = *(bfrag8*)&As[mt * 16 + l15][quad * 8];
        #pragma unroll
        for (int g = 0; g < 3; ++g) b[g] = *(bfrag8*)&Bs[g * 64 + w * 16 + l15][quad * 8];
        #pragma unroll
        for (int mt = 0; mt < 8; ++mt)
            #pragma unroll
            for (int g = 0; g < 3; ++g)
                acc[mt][g] = __builtin_amdgcn_mfma_f32_16x16x32_bf16(a[mt], b[g], acc[mt][g], 0, 0, 0);
        __syncthreads();
    }

    const int hu = q * 64 + w * 16 + l15;
    const float bi = loadv(biou, hu,       f_b);
    const float bo = loadv(biou, 256 + hu, f_b);
    const float bu = loadv(biou, 512 + hu, f_b);
    #pragma unroll
    for (int mt = 0; mt < 8; ++mt) {
        #pragma unroll
        for (int r = 0; r < 4; ++r) {
            int node = m0 + mt * 16 + quad * 4 + r;
            if (node < NN) {
                size_t off = (size_t)node * 256 + hu;
                float iv = acc[mt][0][r] + bi;
                float ov = acc[mt][1][r] + bo;
                float uv = acc[mt][2][r] + bu;
                float cg = cagg ? bf2f(cagg[off]) : 0.f;
                float cn = sigf(iv) * tanhf(uv) + cg;
                float hn = sigf(ov) * tanhf(cn);
                hdst[off] = f2bf(hn);
                cdst[off] = f2bf(cn);
            }
        }
    }
}

// tail: levels d=5..0 + final linear; one block/graph; LDS/register resident.
__global__ __launch_bounds__(256, 1) void tail_kernel(
    const int* __restrict__ tokLvl, const u16* __restrict__ embb,
    const u16* __restrict__ wuc, const void* __restrict__ biou,
    const u16* __restrict__ ufc, const void* __restrict__ ufb,
    const u16* __restrict__ hB, const u16* __restrict__ cB,
    const int* __restrict__ cnt, const int* __restrict__ bucket,
    const void* __restrict__ lw, const void* __restrict__ lb,
    float* __restrict__ out, const int* __restrict__ flags)
{
    __shared__ u16 hs[64][264];    // child h; fc overwrites; parent h overwrites
    __shared__ u16 hts[32][264];   // htild (MFMA-A padded)
    const int t = threadIdx.x;
    const int g = blockIdx.x;
    const int w = t >> 6, lane = t & 63, quad = lane >> 4, l15 = lane & 15;
    const int f_uf = flags[3], f_b = flags[1], f_lw = flags[4];

    // load child h of d=5 (level 6, 64 rows/graph) from hB into hs
    for (int i = t; i < 64 * 32; i += 256) {
        int j = i >> 5, seg = i & 31;
        *(uint4*)&hs[j][seg * 8] =
            *(const uint4*)(hB + (((size_t)((g << 6) + j)) << 8) + seg * 8);
    }
    __syncthreads();

    float cReg[2][4][4];           // parent c carried fp32 in registers

    for (int d = 5; d >= 0; --d) {
        const int ncr = 1 << (d + 1);
        const int np  = 1 << d;
        const int lvb = LB(d) + (g << d);

        // ---- stage1: facc = h_ch @ Ufw^T (A: hs LDS, B: Ufc global) --------
        ffrag4 facc[4][4];
        #pragma unroll
        for (int i = 0; i < 4; ++i)
            #pragma unroll
            for (int j = 0; j < 4; ++j) facc[i][j] = (ffrag4)0.f;
        #pragma unroll
        for (int c = 0; c < 8; ++c) {
            bfrag8 a[4], b[4];
            #pragma unroll
            for (int mt = 0; mt < 4; ++mt)
                a[mt] = *(const bfrag8*)&hs[mt * 16 + l15][c * 32 + quad * 8];
            #pragma unroll
            for (int nt = 0; nt < 4; ++nt)
                b[nt] = *(const bfrag8*)(ufc + ((size_t)c * 256 + w * 64 + nt * 16 + l15) * 32 + quad * 8);
            #pragma unroll
            for (int mt = 0; mt < 4; ++mt)
                #pragma unroll
                for (int nt = 0; nt < 4; ++nt)
                    facc[mt][nt] = __builtin_amdgcn_mfma_f32_16x16x32_bf16(a[mt], b[nt], facc[mt][nt], 0, 0, 0);
        }
        // fc = sig(raw+b) * c   (c: registers, or global cB at d=5)
        #pragma unroll
        for (int nt = 0; nt < 4; ++nt) {
            int hu = w * 64 + nt * 16 + l15;
            float fb = loadv(ufb, hu, f_uf);
            #pragma unroll
            for (int mt = 0; mt < 4; ++mt) {
                #pragma unroll
                for (int r = 0; r < 4; ++r) {
                    int j = mt * 16 + quad * 4 + r;
                    float cv;
                    if (d == 5)
                        cv = bf2f(cB[(((size_t)((g << 6) + j)) << 8) + hu]);
                    else
                        cv = (j < ncr && mt < 2) ? cReg[mt][nt][r] : 0.f;
                    facc[mt][nt][r] = sigf(facc[mt][nt][r] + fb) * cv;
                }
            }
        }

        // ---- stage2a: htild gather (hs h -> hts) ---------------------------
        {
            const int col = t & 127;
            for (int pi = t >> 7; pi < np; pi += 2) {
                int nc = min(cnt[lvb + pi], KCAP);
                const int* bk = bucket + (size_t)(lvb + pi) * KCAP;
                float h0 = 0.f, h1 = 0.f;
                for (int ci = 0; ci < nc; ++ci) {
                    int j = bk[ci] & (ncr - 1);
                    u32 hv = *(const u32*)&hs[j][col * 2];
                    h0 += bf2f((u16)(hv & 0xffff));
                    h1 += bf2f((u16)(hv >> 16));
                }
                *(u32*)&hts[pi][col * 2] = (u32)f2bf(h0) | ((u32)f2bf(h1) << 16);
            }
        }
        __syncthreads();   // B1: hts ready; all hs h-reads done

        // ---- overwrite hs child rows with fc -------------------------------
        #pragma unroll
        for (int nt = 0; nt < 4; ++nt) {
            int hu = w * 64 + nt * 16 + l15;
            #pragma unroll
            for (int mt = 0; mt < 4; ++mt) {
                #pragma unroll
                for (int r = 0; r < 4; ++r) {
                    int j = mt * 16 + quad * 4 + r;
                    if (j < ncr) hs[j][hu] = f2bf(facc[mt][nt][r]);
                }
            }
        }
        __syncthreads();   // B2: fc visible

        // ---- stage2b: cagg gather into registers (stage3 epilogue layout) --
        float cagReg[2][4][4];
        #pragma unroll
        for (int mt = 0; mt < 2; ++mt) {
            #pragma unroll
            for (int r = 0; r < 4; ++r) {
                int p = mt * 16 + quad * 4 + r;
                #pragma unroll
                for (int st = 0; st < 4; ++st) cagReg[mt][st][r] = 0.f;
                if (p < np) {
                    int nc = min(cnt[lvb + p], KCAP);
                    const int* bk = bucket + (size_t)(lvb + p) * KCAP;
                    for (int ci = 0; ci < nc; ++ci) {
                        int j = bk[ci] & (ncr - 1);
                        #pragma unroll
                        for (int st = 0; st < 4; ++st)
                            cagReg[mt][st][r] += bf2f(hs[j][w * 64 + st * 16 + l15]);
                    }
                }
            }
        }
        __syncthreads();   // B3: stage2b hs reads done before epilogue writes

        // ---- stage3: [embb|hts] @ WUc + gates ------------------------------
        int tok0 = tokLvl[lvb + min(l15, np - 1)];
        int tok1 = tokLvl[lvb + min(16 + l15, np - 1)];
        ffrag4 acc[2][12];
        #pragma unroll
        for (int i = 0; i < 2; ++i)
            #pragma unroll
            for (int j = 0; j < 12; ++j) acc[i][j] = (ffrag4)0.f;
        #pragma unroll
        for (int c = 0; c < 16; ++c) {
            bfrag8 a[2], b[12];
            if (c < 8) {
                a[0] = *(const bfrag8*)(embb + (size_t)tok0 * 256 + c * 32 + quad * 8);
                a[1] = *(const bfrag8*)(embb + (size_t)tok1 * 256 + c * 32 + quad * 8);
            } else {
                a[0] = *(const bfrag8*)&hts[l15][(c - 8) * 32 + quad * 8];
                a[1] = *(const bfrag8*)&hts[16 + l15][(c - 8) * 32 + quad * 8];
            }
            #pragma unroll
            for (int g3 = 0; g3 < 3; ++g3)
                #pragma unroll
                for (int st = 0; st < 4; ++st)
                    b[g3 * 4 + st] = *(const bfrag8*)(wuc + ((size_t)c * 768 + g3 * 256 + w * 64 + st * 16 + l15) * 32 + quad * 8);
            #pragma unroll
            for (int mt = 0; mt < 2; ++mt)
                #pragma unroll
                for (int nt = 0; nt < 12; ++nt)
                    acc[mt][nt] = __builtin_amdgcn_mfma_f32_16x16x32_bf16(a[mt], b[nt], acc[mt][nt], 0, 0, 0);
        }
        #pragma unroll
        for (int st = 0; st < 4; ++st) {
            int hu = w * 64 + st * 16 + l15;
            float bi = loadv(biou, hu,       f_b);
            float bo = loadv(biou, 256 + hu, f_b);
            float bu = loadv(biou, 512 + hu, f_b);
            #pragma unroll
            for (int mt = 0; mt < 2; ++mt) {
                #pragma unroll
                for (int r = 0; r < 4; ++r) {
                    int p = mt * 16 + quad * 4 + r;
                    float iv = acc[mt][0 * 4 + st][r] + bi;
                    float ov = acc[mt][1 * 4 + st][r] + bo;
                    float uv = acc[mt][2 * 4 + st][r] + bu;
                    float cn = sigf(iv) * tanhf(uv) + cagReg[mt][st][r];
                    float hn = sigf(ov) * tanhf(cn);
                    cReg[mt][st][r] = cn;                 // fp32, stays resident
                    if (p < np) hs[p][hu] = f2bf(hn);     // parent h over dead rows
                }
            }
        }
        __syncthreads();   // B4: end of level
    }

    // ---- final linear: out[g,:] = h_root @ lw^T + lb (h_root = hs row 0) ---
    if (t < NCLS) {
        float acc = 0.f;
        for (int k = 0; k < 256; ++k)
            acc += loadv(lw, t * 256 + k, f_lw) * bf2f(hs[0][k]);
        out[(size_t)g * NCLS + t] = acc + loadv(lb, t, f_lw);
    }
}

__global__ void fill_kernel(float* out, int n, float v) {
    int i = blockIdx.x * 256 + threadIdx.x;
    if (i < n) out[i] = v;
}

// ============================ launcher =====================================
extern "C" void kernel_launch(void* const* d_in, const int* in_sizes, int n_in,
                              void* d_out, int out_size, void* d_ws, size_t ws_size,
                              hipStream_t stream)
{
    float* out = (float*)d_out;

    static const int exp_sizes[10] = {131040, 131040, 5120000, 196608, 196608,
                                      768, 65536, 256, 26624, 104};
    bool shapes_ok = (n_in == 10) && (out_size == B_G * NCLS);
    for (int i = 0; i < 10 && shapes_ok; ++i)
        if (in_sizes[i] != exp_sizes[i]) shapes_ok = false;
    if (!shapes_ok) {
        fill_kernel<<<(out_size + 255) / 256, 256, 0, stream>>>(out, out_size, 2.0f);
        return;
    }

    const int* x     = (const int*)d_in[0];
    const int* par   = (const int*)d_in[1];
    const void* emb  = d_in[2];
    const void* Wiou = d_in[3];
    const void* Uiou = d_in[4];
    const void* biou = d_in[5];
    const void* Ufw  = d_in[6];
    const void* Ufb  = d_in[7];
    const void* lw   = d_in[8];
    const void* lb   = d_in[9];

    // -------- workspace layout (byte offsets); total 152,453,184 B --------
    char* W = (char*)d_ws;
    u16* hA     = (u16*)(W + 0);              // bf16 [65536][256] odd levels
    u16* hB     = (u16*)(W + 33554432);       // bf16 [32768][256] even levels
    u16* cA     = (u16*)(W + 50331648);       // bf16 [65536][256] (fc in-place)
    u16* cB     = (u16*)(W + 83886080);       // bf16 [32768][256]
    u16* htild  = (u16*)(W + 100663296);      // bf16 [32768][256]
    u16* cagg   = (u16*)(W + 117440512);      // bf16 [32768][256]
    u16* WUc    = (u16*)(W + 134217728);      // bf16 [16][768][32]
    u16* Ufc    = (u16*)(W + 135004160);      // bf16 [8][256][32]
    int* tokLvl = (int*)(W + 135135232);      // int  [131072]
    int* cnt    = (int*)(W + 135659520);      // int  [65536]
    int* bucket = (int*)(W + 135921664);      // int  [65536*KCAP]
    u16* embb   = (u16*)(W + 142213120);      // bf16 [20000][256]
    int* flags  = (int*)(W + 152453120);      // int  [16]
    const size_t NEED = 152453184;            // <= 152,961,088 known-fit (r7)
    if (ws_size < NEED) {
        fill_kernel<<<(out_size + 255) / 256, 256, 0, stream>>>(out, out_size, 1.0f);
        return;
    }

    hipMemsetAsync(cnt, 0, 65536 * sizeof(int), stream);
    probe_kernel<<<1, 1, 0, stream>>>(emb, Wiou, Uiou, Ufw, lw, x, par, flags);
    prep_kernel<<<(NTOT + 255) / 256, 256, 0, stream>>>(x, par, tokLvl, cnt, bucket, flags);
    embconv_kernel<<<2500, 256, 0, stream>>>(emb, embb, flags);
    wuc_kernel<<<1536, 256, 0, stream>>>(Wiou, Uiou, WUc, flags);
    ufc_kernel<<<256, 256, 0, stream>>>(Ufw, Ufc, flags);

    // leaves d=11 (odd parity -> hA/cA), K=256
    gemm2_kernel<<<dim3(512, 4), 256, 0, stream>>>(
        8, 65536, tokLvl + LB(11), embb, WUc, biou,
        nullptr, nullptr, hA, cA, flags);

    for (int d = 10; d >= 6; --d) {
        const int cl = d + 1;
        const int NC = B_G << cl;
        const int NN = B_G << d;
        const u16* hch = (cl & 1) ? hA : hB;
        u16*       cch = (cl & 1) ? cA : cB;   // becomes fc in-place
        u16* hdst = (d & 1) ? hA : hB;
        u16* cdst = (d & 1) ? cA : cB;
        gemm1_kernel<<<NC / 64, 256, 0, stream>>>(hch, cch, Ufc, Ufb, flags);
        agg_kernel<<<(NN + 1) / 2, 256, 0, stream>>>(
            NN, (const u32*)hch, (const u32*)cch,
            cnt + LB(d), bucket + (size_t)LB(d) * KCAP,
            (u32*)htild, (u32*)cagg);
        gemm2_kernel<<<dim3((NN + 127) / 128, 4), 256, 0, stream>>>(
            16, NN, tokLvl + LB(d), embb, WUc, biou,
            htild, cagg, hdst, cdst, flags);
    }

    // levels d=5..0 + final linear: one block per graph, LDS-resident
    tail_kernel<<<B_G, 256, 0, stream>>>(
        tokLvl, embb, WUc, biou, Ufc, Ufb,
        hB, cB, cnt, bucket, lw, lb, out, flags);
}

// Round 14
// 795.033 us; speedup vs baseline: 1.1110x; 1.0801x over previous
//
#include <hip/hip_runtime.h>
#include <hip/hip_bf16.h>

// DGL child-sum TreeLSTM, MFMA path, round 14.
// Tail (d=5..0 + final linear): one block/graph, FULLY LDS-resident state
// (hs/cs child+parent h,c; hts/cts htild,cagg; 101KB), no register carries
// across levels, B-frags loaded one-at-a-time -> no spills (r13: VGPR=256 +
// 25MB scratch WRITE_SIZE at 1-block/CU was the 3x slowdown).
// 3 barriers/level. Head unchanged from r11/r13.
// Facts: inputs fp32 (probed), x/par int32, out fp32, ws >= 152,961,088 B.

#define B_G     32
#define NPG     4095
#define NTOT    (B_G * NPG)
#define NCLS    104
#define VOCAB   20000
#define PAD_TOK 19999
#define KCAP    24
#define LB(d)   (32 * ((1 << (d)) - 1))   // level base in level-major order

typedef unsigned short u16;
typedef unsigned int   u32;
typedef __attribute__((ext_vector_type(8))) short bfrag8;  // 8 bf16
typedef __attribute__((ext_vector_type(4))) float ffrag4;  // 4 f32

__device__ __forceinline__ float bf2f(u16 v) {
    union { u32 u; float f; } x; x.u = ((u32)v) << 16; return x.f;
}
__device__ __forceinline__ u16 f2bf(float f) {
    union { __hip_bfloat16 h; u16 u; } c; c.h = __float2bfloat16(f); return c.u;
}
__device__ __forceinline__ float loadv(const void* b, int i, int isf32) {
    return isf32 ? ((const float*)b)[i] : bf2f(((const u16*)b)[i]);
}
__device__ __forceinline__ float sigf(float x) { return 1.f / (1.f + __expf(-x)); }

// --------------------------- dtype probe -----------------------------------
__global__ void probe_kernel(const void* emb, const void* Wiou, const void* Uiou,
                             const void* Ufw, const void* lw,
                             const int* x32, const int* par32, int* flags)
{
    if (threadIdx.x != 0 || blockIdx.x != 0) return;
    const void* ptrs[5] = { emb, Wiou, Uiou, Ufw, lw };
    for (int i = 0; i < 5; ++i) {
        const u16* p = (const u16*)ptrs[i];
        int big = 0;
        for (int k = 0; k < 128; ++k) {
            u32 e = (((u32)p[k]) << 16 >> 23) & 0xFF;
            if (e >= 129) ++big;
        }
        flags[i] = (big >= 4) ? 1 : 0;     // 1 => fp32
    }
    int zx = 1;
    for (int k = 1; k <= 15; k += 2) if (x32[k] != 0) zx = 0;
    flags[5] = zx;                         // 1 => x int64
    flags[6] = (par32[3] == 0 && par32[5] == 0) ? 1 : 0;  // 1 => par int64
}

// ------------------- prep: tokens + per-parent child lists ------------------
__global__ __launch_bounds__(256) void prep_kernel(
    const int* __restrict__ x, const int* __restrict__ par,
    int* __restrict__ tokLvl, int* __restrict__ cnt, int* __restrict__ bucket,
    const int* __restrict__ flags)
{
    int gid = blockIdx.x * 256 + threadIdx.x;
    if (gid >= NTOT) return;
    int g     = (int)((u32)gid / NPG);
    int local = gid - g * NPG;
    int v  = local + 1;
    int d  = 31 - __clz(v);
    int j  = local - ((1 << d) - 1);
    int tok = flags[5] ? x[2 * gid] : x[gid];
    if (tok < 0 || tok >= VOCAB) tok = PAD_TOK;
    tokLvl[LB(d) + (g << d) + j] = tok;
    if (local > 0) {
        int p  = flags[6] ? par[2 * gid] : par[gid];
        p = max(0, min(p, NTOT - 1));
        int pg = (int)((u32)p / NPG);
        int pl = p - pg * NPG;
        int pd = d - 1;
        int ps = LB(pd) + (pg << pd) + (pl - ((1 << pd) - 1));
        ps = max(0, min(ps, 65503));
        int slot = atomicAdd(&cnt[ps], 1);
        if (slot < KCAP) bucket[(size_t)ps * KCAP + slot] = (g << d) + j;
    }
}

// emb -> bf16 table, PAD row zeroed
__global__ __launch_bounds__(256) void embconv_kernel(
    const void* __restrict__ emb, u16* __restrict__ embb,
    const int* __restrict__ flags)
{
    int i8 = (blockIdx.x * 256 + threadIdx.x) * 8;
    if (i8 >= VOCAB * 256) return;
    u16 v[8];
    if ((i8 >> 8) == PAD_TOK) {
        #pragma unroll
        for (int s = 0; s < 8; ++s) v[s] = 0;
    } else if (flags[0]) {
        const float* e = (const float*)emb + i8;
        float4 a = *(const float4*)e;
        float4 b = *(const float4*)(e + 4);
        v[0]=f2bf(a.x); v[1]=f2bf(a.y); v[2]=f2bf(a.z); v[3]=f2bf(a.w);
        v[4]=f2bf(b.x); v[5]=f2bf(b.y); v[6]=f2bf(b.z); v[7]=f2bf(b.w);
    } else {
        *(uint4*)v = *(const uint4*)((const u16*)emb + i8);
    }
    *(uint4*)(embb + i8) = *(uint4*)v;
}

// combined [Wiou|Uiou] -> bf16, K-chunked wuc[c][768][32], c=0..15
__global__ __launch_bounds__(256) void wuc_kernel(
    const void* __restrict__ Wiou, const void* __restrict__ Uiou,
    u16* __restrict__ wuc, const int* __restrict__ flags)
{
    int idx = blockIdx.x * 256 + threadIdx.x;
    if (idx >= 16 * 768 * 32) return;
    int c   = idx / 24576;
    int rem = idx - c * 24576;
    int out = rem >> 5;
    int kk  = rem & 31;
    int k   = c * 32 + kk;
    float v = (k < 256) ? loadv(Wiou, out * 256 + k, flags[1])
                        : loadv(Uiou, out * 256 + (k - 256), flags[2]);
    wuc[idx] = f2bf(v);
}

// Ufw -> bf16, chunked ufc[c][256][32], c=0..7
__global__ __launch_bounds__(256) void ufc_kernel(
    const void* __restrict__ Ufw, u16* __restrict__ ufc,
    const int* __restrict__ flags)
{
    int idx = blockIdx.x * 256 + threadIdx.x;
    if (idx >= 8 * 256 * 32) return;
    int c   = idx >> 13;
    int rem = idx & 8191;
    int out = rem >> 5;
    int kk  = rem & 31;
    ufc[idx] = f2bf(loadv(Ufw, out * 256 + c * 32 + kk, flags[3]));
}

// GEMM1: fc = sigmoid(h_ch @ Ufw^T + b) * c_ch, IN-PLACE over cbuf. M=64.
__global__ __launch_bounds__(256, 3) void gemm1_kernel(
    const u16* __restrict__ hch, u16* cbuf,
    const u16* __restrict__ ufc, const void* __restrict__ ufb,
    const int* __restrict__ flags)
{
    __shared__ u16 As[64][40];
    __shared__ u16 Bs[256][40];
    const int t = threadIdx.x;
    const int w = t >> 6, lane = t & 63, quad = lane >> 4, l15 = lane & 15;
    const int m0 = blockIdx.x * 64;
    const int f_uf = flags[3];

    ffrag4 acc[4][4];
    #pragma unroll
    for (int i = 0; i < 4; ++i)
        #pragma unroll
        for (int j = 0; j < 4; ++j) acc[i][j] = (ffrag4)0.f;

    const int arow = t >> 2, aseg = t & 3;
    for (int c = 0; c < 8; ++c) {
        *(uint4*)&As[arow][aseg * 8] =
            *(const uint4*)(hch + (size_t)(m0 + arow) * 256 + c * 32 + aseg * 8);
        #pragma unroll
        for (int r16 = 0; r16 < 4; ++r16) {
            int row = r16 * 64 + arow;
            *(uint4*)&Bs[row][aseg * 8] =
                *(const uint4*)(ufc + ((size_t)c * 256 + row) * 32 + aseg * 8);
        }
        __syncthreads();
        bfrag8 a[4], b[4];
        #pragma unroll
        for (int mt = 0; mt < 4; ++mt) a[mt] = *(bfrag8*)&As[mt * 16 + l15][quad * 8];
        #pragma unroll
        for (int nt = 0; nt < 4; ++nt) b[nt] = *(bfrag8*)&Bs[w * 64 + nt * 16 + l15][quad * 8];
        #pragma unroll
        for (int mt = 0; mt < 4; ++mt)
            #pragma unroll
            for (int nt = 0; nt < 4; ++nt)
                acc[mt][nt] = __builtin_amdgcn_mfma_f32_16x16x32_bf16(a[mt], b[nt], acc[mt][nt], 0, 0, 0);
        __syncthreads();
    }

    #pragma unroll
    for (int nt = 0; nt < 4; ++nt) {
        int hu = w * 64 + nt * 16 + l15;
        float fb = loadv(ufb, hu, f_uf);
        #pragma unroll
        for (int mt = 0; mt < 4; ++mt) {
            #pragma unroll
            for (int r = 0; r < 4; ++r) {
                int node = m0 + mt * 16 + quad * 4 + r;
                size_t off = (size_t)node * 256 + hu;
                float f = sigf(acc[mt][nt][r] + fb);
                cbuf[off] = f2bf(f * bf2f(cbuf[off]));
            }
        }
    }
}

// agg: htild[p] = sum h_child, cagg[p] = sum fc_child. Coalesced.
__global__ __launch_bounds__(256) void agg_kernel(
    int NN, const u32* __restrict__ hch32, const u32* __restrict__ fcch32,
    const int* __restrict__ cnt_d, const int* __restrict__ bucket_d,
    u32* __restrict__ htild32, u32* __restrict__ cagg32)
{
    int pi  = blockIdx.x * 2 + (threadIdx.x >> 7);
    int col = threadIdx.x & 127;
    if (pi >= NN) return;
    int nc = min(cnt_d[pi], KCAP);
    float h0 = 0.f, h1 = 0.f, c0 = 0.f, c1 = 0.f;
    for (int ci = 0; ci < nc; ++ci) {
        int ch = bucket_d[(size_t)pi * KCAP + ci];
        u32 hv = hch32[(size_t)ch * 128 + col];
        u32 fv = fcch32[(size_t)ch * 128 + col];
        h0 += bf2f((u16)(hv & 0xffff)); h1 += bf2f((u16)(hv >> 16));
        c0 += bf2f((u16)(fv & 0xffff)); c1 += bf2f((u16)(fv >> 16));
    }
    htild32[(size_t)pi * 128 + col] = (u32)f2bf(h0) | ((u32)f2bf(h1) << 16);
    cagg32[(size_t)pi * 128 + col]  = (u32)f2bf(c0) | ((u32)f2bf(c1) << 16);
}

// GEMM2: IOU = [embb[x] | Htild] @ [Wiou|Uiou]^T + gates. M=128, N=192/block.
__global__ __launch_bounds__(256, 3) void gemm2_kernel(
    int nchunk, int NN,
    const int* __restrict__ tokLvl_d, const u16* __restrict__ embb,
    const u16* __restrict__ wuc, const void* __restrict__ biou,
    const u16* __restrict__ htild, const u16* __restrict__ cagg,
    u16* __restrict__ hdst, u16* __restrict__ cdst,
    const int* __restrict__ flags)
{
    __shared__ u16 As[128][40];
    __shared__ u16 Bs[192][40];
    __shared__ int toks[128];
    const int t = threadIdx.x;
    const int w = t >> 6, lane = t & 63, quad = lane >> 4, l15 = lane & 15;
    const int m0 = blockIdx.x * 128;
    const int q  = blockIdx.y;
    const int f_b = flags[1];

    if (t < 128) toks[t] = tokLvl_d[m0 + t];
    __syncthreads();

    ffrag4 acc[8][3];
    #pragma unroll
    for (int i = 0; i < 8; ++i)
        #pragma unroll
        for (int j = 0; j < 3; ++j) acc[i][j] = (ffrag4)0.f;

    const int arow = t >> 1, ac0 = (t & 1) * 16;
    const int brow = t >> 2, bseg = t & 3;
    for (int c = 0; c < nchunk; ++c) {
        if (c < 8) {
            const u16* e = embb + (size_t)toks[arow] * 256 + c * 32 + ac0;
            *(uint4*)&As[arow][ac0]     = *(const uint4*)e;
            *(uint4*)&As[arow][ac0 + 8] = *(const uint4*)(e + 8);
        } else {
            const u16* hsrc = htild + (size_t)(m0 + arow) * 256 + (c - 8) * 32 + ac0;
            *(uint4*)&As[arow][ac0]     = *(const uint4*)hsrc;
            *(uint4*)&As[arow][ac0 + 8] = *(const uint4*)(hsrc + 8);
        }
        #pragma unroll
        for (int g = 0; g < 3; ++g) {
            *(uint4*)&Bs[g * 64 + brow][bseg * 8] =
                *(const uint4*)(wuc + ((size_t)c * 768 + g * 256 + q * 64 + brow) * 32 + bseg * 8);
        }
        __syncthreads();
        bfrag8 a[8], b[3];
        #pragma unroll
        for (int mt = 0; mt < 8; ++mt) a[mt] = *(bfrag8*)&As[mt * 16 + l15][quad * 8];
        #pragma unroll
        for (int g = 0; g < 3; ++g) b[g] = *(bfrag8*)&Bs[g * 64 + w * 16 + l15][quad * 8];
        #pragma unroll
        for (int mt = 0; mt < 8; ++mt)
            #pragma unroll
            for (int g = 0; g < 3; ++g)
                acc[mt][g] = __builtin_amdgcn_mfma_f32_16x16x32_bf16(a[mt], b[g], acc[mt][g], 0, 0, 0);
        __syncthreads();
    }

    const int hu = q * 64 + w * 16 + l15;
    const float bi = loadv(biou, hu,       f_b);
    const float bo = loadv(biou, 256 + hu, f_b);
    const float bu = loadv(biou, 512 + hu, f_b);
    #pragma unroll
    for (int mt = 0; mt < 8; ++mt) {
        #pragma unroll
        for (int r = 0; r < 4; ++r) {
            int node = m0 + mt * 16 + quad * 4 + r;
            if (node < NN) {
                size_t off = (size_t)node * 256 + hu;
                float iv = acc[mt][0][r] + bi;
                float ov = acc[mt][1][r] + bo;
                float uv = acc[mt][2][r] + bu;
                float cg = cagg ? bf2f(cagg[off]) : 0.f;
                float cn = sigf(iv) * tanhf(uv) + cg;
                float hn = sigf(ov) * tanhf(cn);
                hdst[off] = f2bf(hn);
                cdst[off] = f2bf(cn);
            }
        }
    }
}

// tail: levels d=5..0 + final linear; one block/graph; ALL state in LDS.
__global__ __launch_bounds__(256, 1) void tail_kernel(
    const int* __restrict__ tokLvl, const u16* __restrict__ embb,
    const u16* __restrict__ wuc, const void* __restrict__ biou,
    const u16* __restrict__ ufc, const void* __restrict__ ufb,
    const u16* __restrict__ hB, const u16* __restrict__ cB,
    const int* __restrict__ cnt, const int* __restrict__ bucket,
    const void* __restrict__ lw, const void* __restrict__ lb,
    float* __restrict__ out, const int* __restrict__ flags)
{
    __shared__ u16 hs[64][264];    // child h; parent h overwrites rows < np
    __shared__ u16 cs[64][264];    // child c -> fc (stage1) -> parent c
    __shared__ u16 hts[32][264];   // htild
    __shared__ u16 cts[32][264];   // cagg
    const int t = threadIdx.x;
    const int g = blockIdx.x;
    const int w = t >> 6, lane = t & 63, quad = lane >> 4, l15 = lane & 15;
    const int f_uf = flags[3], f_b = flags[1], f_lw = flags[4];

    // preload child h,c of d=5 (level 6: 64 rows/graph)
    for (int i = t; i < 64 * 32; i += 256) {
        int j = i >> 5, seg = i & 31;
        size_t off = (((size_t)((g << 6) + j)) << 8) + seg * 8;
        *(uint4*)&hs[j][seg * 8] = *(const uint4*)(hB + off);
        *(uint4*)&cs[j][seg * 8] = *(const uint4*)(cB + off);
    }
    __syncthreads();

    for (int d = 5; d >= 0; --d) {
        const int ncr = 1 << (d + 1);
        const int np  = 1 << d;
        const int lvb = LB(d) + (g << d);

        // ---- stage1: cs[j] <- sig(hs[j]@Ufw^T + b) * cs[j]  (same-thread RMW)
        {
            ffrag4 facc[4][4];
            #pragma unroll
            for (int i = 0; i < 4; ++i)
                #pragma unroll
                for (int j = 0; j < 4; ++j) facc[i][j] = (ffrag4)0.f;
            #pragma unroll
            for (int c = 0; c < 8; ++c) {
                bfrag8 a[4];
                #pragma unroll
                for (int mt = 0; mt < 4; ++mt)
                    a[mt] = *(const bfrag8*)&hs[mt * 16 + l15][c * 32 + quad * 8];
                #pragma unroll
                for (int nt = 0; nt < 4; ++nt) {
                    bfrag8 b = *(const bfrag8*)(ufc + ((size_t)c * 256 + w * 64 + nt * 16 + l15) * 32 + quad * 8);
                    #pragma unroll
                    for (int mt = 0; mt < 4; ++mt)
                        facc[mt][nt] = __builtin_amdgcn_mfma_f32_16x16x32_bf16(a[mt], b, facc[mt][nt], 0, 0, 0);
                }
            }
            #pragma unroll
            for (int nt = 0; nt < 4; ++nt) {
                int hu = w * 64 + nt * 16 + l15;
                float fb = loadv(ufb, hu, f_uf);
                #pragma unroll
                for (int mt = 0; mt < 4; ++mt) {
                    #pragma unroll
                    for (int r = 0; r < 4; ++r) {
                        int j = mt * 16 + quad * 4 + r;
                        if (j < ncr) {
                            float f = sigf(facc[mt][nt][r] + fb);
                            cs[j][hu] = f2bf(f * bf2f(cs[j][hu]));
                        }
                    }
                }
            }
        }
        __syncthreads();   // B1: fc visible; hs still child h

        // ---- stage2: gather htild (hs) + cagg (cs) per parent --------------
        {
            const int col = t & 127;
            for (int pi = t >> 7; pi < np; pi += 2) {
                int nc = min(cnt[lvb + pi], KCAP);
                const int* bk = bucket + (size_t)(lvb + pi) * KCAP;
                float h0 = 0.f, h1 = 0.f, c0 = 0.f, c1 = 0.f;
                for (int ci = 0; ci < nc; ++ci) {
                    int j = bk[ci] & (ncr - 1);
                    u32 hv = *(const u32*)&hs[j][col * 2];
                    u32 cv = *(const u32*)&cs[j][col * 2];
                    h0 += bf2f((u16)(hv & 0xffff)); h1 += bf2f((u16)(hv >> 16));
                    c0 += bf2f((u16)(cv & 0xffff)); c1 += bf2f((u16)(cv >> 16));
                }
                *(u32*)&hts[pi][col * 2] = (u32)f2bf(h0) | ((u32)f2bf(h1) << 16);
                *(u32*)&cts[pi][col * 2] = (u32)f2bf(c0) | ((u32)f2bf(c1) << 16);
            }
        }
        __syncthreads();   // B2: hts/cts ready; hs/cs child rows now dead

        // ---- stage3: [embb|hts] @ WUc + gates; write parent h,c to hs,cs ---
        {
            int tok0 = tokLvl[lvb + min(l15, np - 1)];
            int tok1 = tokLvl[lvb + min(16 + l15, np - 1)];
            ffrag4 acc[2][12];
            #pragma unroll
            for (int i = 0; i < 2; ++i)
                #pragma unroll
                for (int j = 0; j < 12; ++j) acc[i][j] = (ffrag4)0.f;
            #pragma unroll
            for (int c = 0; c < 16; ++c) {
                bfrag8 a0, a1;
                if (c < 8) {
                    a0 = *(const bfrag8*)(embb + (size_t)tok0 * 256 + c * 32 + quad * 8);
                    a1 = *(const bfrag8*)(embb + (size_t)tok1 * 256 + c * 32 + quad * 8);
                } else {
                    a0 = *(const bfrag8*)&hts[l15][(c - 8) * 32 + quad * 8];
                    a1 = *(const bfrag8*)&hts[16 + l15][(c - 8) * 32 + quad * 8];
                }
                #pragma unroll
                for (int nt = 0; nt < 12; ++nt) {
                    bfrag8 b = *(const bfrag8*)(wuc + ((size_t)c * 768 + (nt >> 2) * 256 + w * 64 + (nt & 3) * 16 + l15) * 32 + quad * 8);
                    acc[0][nt] = __builtin_amdgcn_mfma_f32_16x16x32_bf16(a0, b, acc[0][nt], 0, 0, 0);
                    acc[1][nt] = __builtin_amdgcn_mfma_f32_16x16x32_bf16(a1, b, acc[1][nt], 0, 0, 0);
                }
            }
            #pragma unroll
            for (int st = 0; st < 4; ++st) {
                int hu = w * 64 + st * 16 + l15;
                float bi = loadv(biou, hu,       f_b);
                float bo = loadv(biou, 256 + hu, f_b);
                float bu = loadv(biou, 512 + hu, f_b);
                #pragma unroll
                for (int mt = 0; mt < 2; ++mt) {
                    #pragma unroll
                    for (int r = 0; r < 4; ++r) {
                        int p = mt * 16 + quad * 4 + r;
                        if (p < np) {
                            float iv = acc[mt][0 * 4 + st][r] + bi;
                            float ov = acc[mt][1 * 4 + st][r] + bo;
                            float uv = acc[mt][2 * 4 + st][r] + bu;
                            float cn = sigf(iv) * tanhf(uv) + bf2f(cts[p][hu]);
                            float hn = sigf(ov) * tanhf(cn);
                            hs[p][hu] = f2bf(hn);
                            cs[p][hu] = f2bf(cn);
                        }
                    }
                }
            }
        }
        __syncthreads();   // B3: end of level
    }

    // ---- final linear: out[g,:] = h_root @ lw^T + lb (h_root = hs row 0) ---
    if (t < NCLS) {
        float acc = 0.f;
        for (int k = 0; k < 256; ++k)
            acc += loadv(lw, t * 256 + k, f_lw) * bf2f(hs[0][k]);
        out[(size_t)g * NCLS + t] = acc + loadv(lb, t, f_lw);
    }
}

__global__ void fill_kernel(float* out, int n, float v) {
    int i = blockIdx.x * 256 + threadIdx.x;
    if (i < n) out[i] = v;
}

// ============================ launcher =====================================
extern "C" void kernel_launch(void* const* d_in, const int* in_sizes, int n_in,
                              void* d_out, int out_size, void* d_ws, size_t ws_size,
                              hipStream_t stream)
{
    float* out = (float*)d_out;

    static const int exp_sizes[10] = {131040, 131040, 5120000, 196608, 196608,
                                      768, 65536, 256, 26624, 104};
    bool shapes_ok = (n_in == 10) && (out_size == B_G * NCLS);
    for (int i = 0; i < 10 && shapes_ok; ++i)
        if (in_sizes[i] != exp_sizes[i]) shapes_ok = false;
    if (!shapes_ok) {
        fill_kernel<<<(out_size + 255) / 256, 256, 0, stream>>>(out, out_size, 2.0f);
        return;
    }

    const int* x     = (const int*)d_in[0];
    const int* par   = (const int*)d_in[1];
    const void* emb  = d_in[2];
    const void* Wiou = d_in[3];
    const void* Uiou = d_in[4];
    const void* biou = d_in[5];
    const void* Ufw  = d_in[6];
    const void* Ufb  = d_in[7];
    const void* lw   = d_in[8];
    const void* lb   = d_in[9];

    // -------- workspace layout (byte offsets); total 152,453,184 B --------
    char* W = (char*)d_ws;
    u16* hA     = (u16*)(W + 0);              // bf16 [65536][256] odd levels
    u16* hB     = (u16*)(W + 33554432);       // bf16 [32768][256] even levels
    u16* cA     = (u16*)(W + 50331648);       // bf16 [65536][256] (fc in-place)
    u16* cB     = (u16*)(W + 83886080);       // bf16 [32768][256]
    u16* htild  = (u16*)(W + 100663296);      // bf16 [32768][256]
    u16* cagg   = (u16*)(W + 117440512);      // bf16 [32768][256]
    u16* WUc    = (u16*)(W + 134217728);      // bf16 [16][768][32]
    u16* Ufc    = (u16*)(W + 135004160);      // bf16 [8][256][32]
    int* tokLvl = (int*)(W + 135135232);      // int  [131072]
    int* cnt    = (int*)(W + 135659520);      // int  [65536]
    int* bucket = (int*)(W + 135921664);      // int  [65536*KCAP]
    u16* embb   = (u16*)(W + 142213120);      // bf16 [20000][256]
    int* flags  = (int*)(W + 152453120);      // int  [16]
    const size_t NEED = 152453184;            // <= 152,961,088 known-fit (r7)
    if (ws_size < NEED) {
        fill_kernel<<<(out_size + 255) / 256, 256, 0, stream>>>(out, out_size, 1.0f);
        return;
    }

    hipMemsetAsync(cnt, 0, 65536 * sizeof(int), stream);
    probe_kernel<<<1, 1, 0, stream>>>(emb, Wiou, Uiou, Ufw, lw, x, par, flags);
    prep_kernel<<<(NTOT + 255) / 256, 256, 0, stream>>>(x, par, tokLvl, cnt, bucket, flags);
    embconv_kernel<<<2500, 256, 0, stream>>>(emb, embb, flags);
    wuc_kernel<<<1536, 256, 0, stream>>>(Wiou, Uiou, WUc, flags);
    ufc_kernel<<<256, 256, 0, stream>>>(Ufw, Ufc, flags);

    // leaves d=11 (odd parity -> hA/cA), K=256
    gemm2_kernel<<<dim3(512, 4), 256, 0, stream>>>(
        8, 65536, tokLvl + LB(11), embb, WUc, biou,
        nullptr, nullptr, hA, cA, flags);

    for (int d = 10; d >= 6; --d) {
        const int cl = d + 1;
        const int NC = B_G << cl;
        const int NN = B_G << d;
        const u16* hch = (cl & 1) ? hA : hB;
        u16*       cch = (cl & 1) ? cA : cB;   // becomes fc in-place
        u16* hdst = (d & 1) ? hA : hB;
        u16* cdst = (d & 1) ? cA : cB;
        gemm1_kernel<<<NC / 64, 256, 0, stream>>>(hch, cch, Ufc, Ufb, flags);
        agg_kernel<<<(NN + 1) / 2, 256, 0, stream>>>(
            NN, (const u32*)hch, (const u32*)cch,
            cnt + LB(d), bucket + (size_t)LB(d) * KCAP,
            (u32*)htild, (u32*)cagg);
        gemm2_kernel<<<dim3((NN + 127) / 128, 4), 256, 0, stream>>>(
            16, NN, tokLvl + LB(d), embb, WUc, biou,
            htild, cagg, hdst, cdst, flags);
    }

    // levels d=5..0 + final linear: one block per graph, LDS-resident state
    tail_kernel<<<B_G, 256, 0, stream>>>(
        tokLvl, embb, WUc, biou, Ufc, Ufb,
        hB, cB, cnt, bucket, lw, lb, out, flags);
}

// Round 15
// 735.222 us; speedup vs baseline: 1.2014x; 1.0814x over previous
//
#include <hip/hip_runtime.h>
#include <hip/hip_bf16.h>

// DGL child-sum TreeLSTM, MFMA path, round 15 = round 14 + unroll control in
// the tail. r14: tail VGPR=256 (cap) + WRITE_SIZE 21MB in a kernel that
// writes 13KB -> compiler fully unrolled the constant-trip chunk loops (and
// likely the 6-level d-loop), hoisted ~dozens of global B-loads, spilled to
// scratch; at 1 block/CU nothing hides the spill round trips. Fix:
// #pragma unroll 1 on the d-loop, #pragma unroll 2 on chunk loops ->
// bounded lookahead (~16-24 loads in flight), live regs ~200, no spills.
// Facts: inputs fp32 (probed), x/par int32, out fp32, ws >= 152,961,088 B.

#define B_G     32
#define NPG     4095
#define NTOT    (B_G * NPG)
#define NCLS    104
#define VOCAB   20000
#define PAD_TOK 19999
#define KCAP    24
#define LB(d)   (32 * ((1 << (d)) - 1))   // level base in level-major order

typedef unsigned short u16;
typedef unsigned int   u32;
typedef __attribute__((ext_vector_type(8))) short bfrag8;  // 8 bf16
typedef __attribute__((ext_vector_type(4))) float ffrag4;  // 4 f32

__device__ __forceinline__ float bf2f(u16 v) {
    union { u32 u; float f; } x; x.u = ((u32)v) << 16; return x.f;
}
__device__ __forceinline__ u16 f2bf(float f) {
    union { __hip_bfloat16 h; u16 u; } c; c.h = __float2bfloat16(f); return c.u;
}
__device__ __forceinline__ float loadv(const void* b, int i, int isf32) {
    return isf32 ? ((const float*)b)[i] : bf2f(((const u16*)b)[i]);
}
__device__ __forceinline__ float sigf(float x) { return 1.f / (1.f + __expf(-x)); }

// --------------------------- dtype probe -----------------------------------
__global__ void probe_kernel(const void* emb, const void* Wiou, const void* Uiou,
                             const void* Ufw, const void* lw,
                             const int* x32, const int* par32, int* flags)
{
    if (threadIdx.x != 0 || blockIdx.x != 0) return;
    const void* ptrs[5] = { emb, Wiou, Uiou, Ufw, lw };
    for (int i = 0; i < 5; ++i) {
        const u16* p = (const u16*)ptrs[i];
        int big = 0;
        for (int k = 0; k < 128; ++k) {
            u32 e = (((u32)p[k]) << 16 >> 23) & 0xFF;
            if (e >= 129) ++big;
        }
        flags[i] = (big >= 4) ? 1 : 0;     // 1 => fp32
    }
    int zx = 1;
    for (int k = 1; k <= 15; k += 2) if (x32[k] != 0) zx = 0;
    flags[5] = zx;                         // 1 => x int64
    flags[6] = (par32[3] == 0 && par32[5] == 0) ? 1 : 0;  // 1 => par int64
}

// ------------------- prep: tokens + per-parent child lists ------------------
__global__ __launch_bounds__(256) void prep_kernel(
    const int* __restrict__ x, const int* __restrict__ par,
    int* __restrict__ tokLvl, int* __restrict__ cnt, int* __restrict__ bucket,
    const int* __restrict__ flags)
{
    int gid = blockIdx.x * 256 + threadIdx.x;
    if (gid >= NTOT) return;
    int g     = (int)((u32)gid / NPG);
    int local = gid - g * NPG;
    int v  = local + 1;
    int d  = 31 - __clz(v);
    int j  = local - ((1 << d) - 1);
    int tok = flags[5] ? x[2 * gid] : x[gid];
    if (tok < 0 || tok >= VOCAB) tok = PAD_TOK;
    tokLvl[LB(d) + (g << d) + j] = tok;
    if (local > 0) {
        int p  = flags[6] ? par[2 * gid] : par[gid];
        p = max(0, min(p, NTOT - 1));
        int pg = (int)((u32)p / NPG);
        int pl = p - pg * NPG;
        int pd = d - 1;
        int ps = LB(pd) + (pg << pd) + (pl - ((1 << pd) - 1));
        ps = max(0, min(ps, 65503));
        int slot = atomicAdd(&cnt[ps], 1);
        if (slot < KCAP) bucket[(size_t)ps * KCAP + slot] = (g << d) + j;
    }
}

// emb -> bf16 table, PAD row zeroed
__global__ __launch_bounds__(256) void embconv_kernel(
    const void* __restrict__ emb, u16* __restrict__ embb,
    const int* __restrict__ flags)
{
    int i8 = (blockIdx.x * 256 + threadIdx.x) * 8;
    if (i8 >= VOCAB * 256) return;
    u16 v[8];
    if ((i8 >> 8) == PAD_TOK) {
        #pragma unroll
        for (int s = 0; s < 8; ++s) v[s] = 0;
    } else if (flags[0]) {
        const float* e = (const float*)emb + i8;
        float4 a = *(const float4*)e;
        float4 b = *(const float4*)(e + 4);
        v[0]=f2bf(a.x); v[1]=f2bf(a.y); v[2]=f2bf(a.z); v[3]=f2bf(a.w);
        v[4]=f2bf(b.x); v[5]=f2bf(b.y); v[6]=f2bf(b.z); v[7]=f2bf(b.w);
    } else {
        *(uint4*)v = *(const uint4*)((const u16*)emb + i8);
    }
    *(uint4*)(embb + i8) = *(uint4*)v;
}

// combined [Wiou|Uiou] -> bf16, K-chunked wuc[c][768][32], c=0..15
__global__ __launch_bounds__(256) void wuc_kernel(
    const void* __restrict__ Wiou, const void* __restrict__ Uiou,
    u16* __restrict__ wuc, const int* __restrict__ flags)
{
    int idx = blockIdx.x * 256 + threadIdx.x;
    if (idx >= 16 * 768 * 32) return;
    int c   = idx / 24576;
    int rem = idx - c * 24576;
    int out = rem >> 5;
    int kk  = rem & 31;
    int k   = c * 32 + kk;
    float v = (k < 256) ? loadv(Wiou, out * 256 + k, flags[1])
                        : loadv(Uiou, out * 256 + (k - 256), flags[2]);
    wuc[idx] = f2bf(v);
}

// Ufw -> bf16, chunked ufc[c][256][32], c=0..7
__global__ __launch_bounds__(256) void ufc_kernel(
    const void* __restrict__ Ufw, u16* __restrict__ ufc,
    const int* __restrict__ flags)
{
    int idx = blockIdx.x * 256 + threadIdx.x;
    if (idx >= 8 * 256 * 32) return;
    int c   = idx >> 13;
    int rem = idx & 8191;
    int out = rem >> 5;
    int kk  = rem & 31;
    ufc[idx] = f2bf(loadv(Ufw, out * 256 + c * 32 + kk, flags[3]));
}

// GEMM1: fc = sigmoid(h_ch @ Ufw^T + b) * c_ch, IN-PLACE over cbuf. M=64.
__global__ __launch_bounds__(256, 3) void gemm1_kernel(
    const u16* __restrict__ hch, u16* cbuf,
    const u16* __restrict__ ufc, const void* __restrict__ ufb,
    const int* __restrict__ flags)
{
    __shared__ u16 As[64][40];
    __shared__ u16 Bs[256][40];
    const int t = threadIdx.x;
    const int w = t >> 6, lane = t & 63, quad = lane >> 4, l15 = lane & 15;
    const int m0 = blockIdx.x * 64;
    const int f_uf = flags[3];

    ffrag4 acc[4][4];
    #pragma unroll
    for (int i = 0; i < 4; ++i)
        #pragma unroll
        for (int j = 0; j < 4; ++j) acc[i][j] = (ffrag4)0.f;

    const int arow = t >> 2, aseg = t & 3;
    for (int c = 0; c < 8; ++c) {
        *(uint4*)&As[arow][aseg * 8] =
            *(const uint4*)(hch + (size_t)(m0 + arow) * 256 + c * 32 + aseg * 8);
        #pragma unroll
        for (int r16 = 0; r16 < 4; ++r16) {
            int row = r16 * 64 + arow;
            *(uint4*)&Bs[row][aseg * 8] =
                *(const uint4*)(ufc + ((size_t)c * 256 + row) * 32 + aseg * 8);
        }
        __syncthreads();
        bfrag8 a[4], b[4];
        #pragma unroll
        for (int mt = 0; mt < 4; ++mt) a[mt] = *(bfrag8*)&As[mt * 16 + l15][quad * 8];
        #pragma unroll
        for (int nt = 0; nt < 4; ++nt) b[nt] = *(bfrag8*)&Bs[w * 64 + nt * 16 + l15][quad * 8];
        #pragma unroll
        for (int mt = 0; mt < 4; ++mt)
            #pragma unroll
            for (int nt = 0; nt < 4; ++nt)
                acc[mt][nt] = __builtin_amdgcn_mfma_f32_16x16x32_bf16(a[mt], b[nt], acc[mt][nt], 0, 0, 0);
        __syncthreads();
    }

    #pragma unroll
    for (int nt = 0; nt < 4; ++nt) {
        int hu = w * 64 + nt * 16 + l15;
        float fb = loadv(ufb, hu, f_uf);
        #pragma unroll
        for (int mt = 0; mt < 4; ++mt) {
            #pragma unroll
            for (int r = 0; r < 4; ++r) {
                int node = m0 + mt * 16 + quad * 4 + r;
                size_t off = (size_t)node * 256 + hu;
                float f = sigf(acc[mt][nt][r] + fb);
                cbuf[off] = f2bf(f * bf2f(cbuf[off]));
            }
        }
    }
}

// agg: htild[p] = sum h_child, cagg[p] = sum fc_child. Coalesced.
__global__ __launch_bounds__(256) void agg_kernel(
    int NN, const u32* __restrict__ hch32, const u32* __restrict__ fcch32,
    const int* __restrict__ cnt_d, const int* __restrict__ bucket_d,
    u32* __restrict__ htild32, u32* __restrict__ cagg32)
{
    int pi  = blockIdx.x * 2 + (threadIdx.x >> 7);
    int col = threadIdx.x & 127;
    if (pi >= NN) return;
    int nc = min(cnt_d[pi], KCAP);
    float h0 = 0.f, h1 = 0.f, c0 = 0.f, c1 = 0.f;
    for (int ci = 0; ci < nc; ++ci) {
        int ch = bucket_d[(size_t)pi * KCAP + ci];
        u32 hv = hch32[(size_t)ch * 128 + col];
        u32 fv = fcch32[(size_t)ch * 128 + col];
        h0 += bf2f((u16)(hv & 0xffff)); h1 += bf2f((u16)(hv >> 16));
        c0 += bf2f((u16)(fv & 0xffff)); c1 += bf2f((u16)(fv >> 16));
    }
    htild32[(size_t)pi * 128 + col] = (u32)f2bf(h0) | ((u32)f2bf(h1) << 16);
    cagg32[(size_t)pi * 128 + col]  = (u32)f2bf(c0) | ((u32)f2bf(c1) << 16);
}

// GEMM2: IOU = [embb[x] | Htild] @ [Wiou|Uiou]^T + gates. M=128, N=192/block.
__global__ __launch_bounds__(256, 3) void gemm2_kernel(
    int nchunk, int NN,
    const int* __restrict__ tokLvl_d, const u16* __restrict__ embb,
    const u16* __restrict__ wuc, const void* __restrict__ biou,
    const u16* __restrict__ htild, const u16* __restrict__ cagg,
    u16* __restrict__ hdst, u16* __restrict__ cdst,
    const int* __restrict__ flags)
{
    __shared__ u16 As[128][40];
    __shared__ u16 Bs[192][40];
    __shared__ int toks[128];
    const int t = threadIdx.x;
    const int w = t >> 6, lane = t & 63, quad = lane >> 4, l15 = lane & 15;
    const int m0 = blockIdx.x * 128;
    const int q  = blockIdx.y;
    const int f_b = flags[1];

    if (t < 128) toks[t] = tokLvl_d[m0 + t];
    __syncthreads();

    ffrag4 acc[8][3];
    #pragma unroll
    for (int i = 0; i < 8; ++i)
        #pragma unroll
        for (int j = 0; j < 3; ++j) acc[i][j] = (ffrag4)0.f;

    const int arow = t >> 1, ac0 = (t & 1) * 16;
    const int brow = t >> 2, bseg = t & 3;
    for (int c = 0; c < nchunk; ++c) {
        if (c < 8) {
            const u16* e = embb + (size_t)toks[arow] * 256 + c * 32 + ac0;
            *(uint4*)&As[arow][ac0]     = *(const uint4*)e;
            *(uint4*)&As[arow][ac0 + 8] = *(const uint4*)(e + 8);
        } else {
            const u16* hsrc = htild + (size_t)(m0 + arow) * 256 + (c - 8) * 32 + ac0;
            *(uint4*)&As[arow][ac0]     = *(const uint4*)hsrc;
            *(uint4*)&As[arow][ac0 + 8] = *(const uint4*)(hsrc + 8);
        }
        #pragma unroll
        for (int g = 0; g < 3; ++g) {
            *(uint4*)&Bs[g * 64 + brow][bseg * 8] =
                *(const uint4*)(wuc + ((size_t)c * 768 + g * 256 + q * 64 + brow) * 32 + bseg * 8);
        }
        __syncthreads();
        bfrag8 a[8], b[3];
        #pragma unroll
        for (int mt = 0; mt < 8; ++mt) a[mt] = *(bfrag8*)&As[mt * 16 + l15][quad * 8];
        #pragma unroll
        for (int g = 0; g < 3; ++g) b[g] = *(bfrag8*)&Bs[g * 64 + w * 16 + l15][quad * 8];
        #pragma unroll
        for (int mt = 0; mt < 8; ++mt)
            #pragma unroll
            for (int g = 0; g < 3; ++g)
                acc[mt][g] = __builtin_amdgcn_mfma_f32_16x16x32_bf16(a[mt], b[g], acc[mt][g], 0, 0, 0);
        __syncthreads();
    }

    const int hu = q * 64 + w * 16 + l15;
    const float bi = loadv(biou, hu,       f_b);
    const float bo = loadv(biou, 256 + hu, f_b);
    const float bu = loadv(biou, 512 + hu, f_b);
    #pragma unroll
    for (int mt = 0; mt < 8; ++mt) {
        #pragma unroll
        for (int r = 0; r < 4; ++r) {
            int node = m0 + mt * 16 + quad * 4 + r;
            if (node < NN) {
                size_t off = (size_t)node * 256 + hu;
                float iv = acc[mt][0][r] + bi;
                float ov = acc[mt][1][r] + bo;
                float uv = acc[mt][2][r] + bu;
                float cg = cagg ? bf2f(cagg[off]) : 0.f;
                float cn = sigf(iv) * tanhf(uv) + cg;
                float hn = sigf(ov) * tanhf(cn);
                hdst[off] = f2bf(hn);
                cdst[off] = f2bf(cn);
            }
        }
    }
}

// tail: levels d=5..0 + final linear; one block/graph; ALL state in LDS;
// unrolling bounded so global B-loads pipeline without spilling.
__global__ __launch_bounds__(256, 1) void tail_kernel(
    const int* __restrict__ tokLvl, const u16* __restrict__ embb,
    const u16* __restrict__ wuc, const void* __restrict__ biou,
    const u16* __restrict__ ufc, const void* __restrict__ ufb,
    const u16* __restrict__ hB, const u16* __restrict__ cB,
    const int* __restrict__ cnt, const int* __restrict__ bucket,
    const void* __restrict__ lw, const void* __restrict__ lb,
    float* __restrict__ out, const int* __restrict__ flags)
{
    __shared__ u16 hs[64][264];    // child h; parent h overwrites rows < np
    __shared__ u16 cs[64][264];    // child c -> fc (stage1) -> parent c
    __shared__ u16 hts[32][264];   // htild
    __shared__ u16 cts[32][264];   // cagg
    const int t = threadIdx.x;
    const int g = blockIdx.x;
    const int w = t >> 6, lane = t & 63, quad = lane >> 4, l15 = lane & 15;
    const int f_uf = flags[3], f_b = flags[1], f_lw = flags[4];

    // preload child h,c of d=5 (level 6: 64 rows/graph)
    #pragma unroll 1
    for (int i = t; i < 64 * 32; i += 256) {
        int j = i >> 5, seg = i & 31;
        size_t off = (((size_t)((g << 6) + j)) << 8) + seg * 8;
        *(uint4*)&hs[j][seg * 8] = *(const uint4*)(hB + off);
        *(uint4*)&cs[j][seg * 8] = *(const uint4*)(cB + off);
    }
    __syncthreads();

    #pragma unroll 1
    for (int d = 5; d >= 0; --d) {
        const int ncr = 1 << (d + 1);
        const int np  = 1 << d;
        const int lvb = LB(d) + (g << d);

        // ---- stage1: cs[j] <- sig(hs[j]@Ufw^T + b) * cs[j]  (same-thread RMW)
        {
            ffrag4 facc[4][4];
            #pragma unroll
            for (int i = 0; i < 4; ++i)
                #pragma unroll
                for (int j = 0; j < 4; ++j) facc[i][j] = (ffrag4)0.f;
            #pragma unroll 2
            for (int c = 0; c < 8; ++c) {
                bfrag8 a[4];
                #pragma unroll
                for (int mt = 0; mt < 4; ++mt)
                    a[mt] = *(const bfrag8*)&hs[mt * 16 + l15][c * 32 + quad * 8];
                #pragma unroll
                for (int nt = 0; nt < 4; ++nt) {
                    bfrag8 b = *(const bfrag8*)(ufc + ((size_t)c * 256 + w * 64 + nt * 16 + l15) * 32 + quad * 8);
                    #pragma unroll
                    for (int mt = 0; mt < 4; ++mt)
                        facc[mt][nt] = __builtin_amdgcn_mfma_f32_16x16x32_bf16(a[mt], b, facc[mt][nt], 0, 0, 0);
                }
            }
            #pragma unroll
            for (int nt = 0; nt < 4; ++nt) {
                int hu = w * 64 + nt * 16 + l15;
                float fb = loadv(ufb, hu, f_uf);
                #pragma unroll
                for (int mt = 0; mt < 4; ++mt) {
                    #pragma unroll
                    for (int r = 0; r < 4; ++r) {
                        int j = mt * 16 + quad * 4 + r;
                        if (j < ncr) {
                            float f = sigf(facc[mt][nt][r] + fb);
                            cs[j][hu] = f2bf(f * bf2f(cs[j][hu]));
                        }
                    }
                }
            }
        }
        __syncthreads();   // B1: fc visible; hs still child h

        // ---- stage2: gather htild (hs) + cagg (cs) per parent --------------
        {
            const int col = t & 127;
            #pragma unroll 1
            for (int pi = t >> 7; pi < np; pi += 2) {
                int nc = min(cnt[lvb + pi], KCAP);
                const int* bk = bucket + (size_t)(lvb + pi) * KCAP;
                float h0 = 0.f, h1 = 0.f, c0 = 0.f, c1 = 0.f;
                #pragma unroll 1
                for (int ci = 0; ci < nc; ++ci) {
                    int j = bk[ci] & (ncr - 1);
                    u32 hv = *(const u32*)&hs[j][col * 2];
                    u32 cv = *(const u32*)&cs[j][col * 2];
                    h0 += bf2f((u16)(hv & 0xffff)); h1 += bf2f((u16)(hv >> 16));
                    c0 += bf2f((u16)(cv & 0xffff)); c1 += bf2f((u16)(cv >> 16));
                }
                *(u32*)&hts[pi][col * 2] = (u32)f2bf(h0) | ((u32)f2bf(h1) << 16);
                *(u32*)&cts[pi][col * 2] = (u32)f2bf(c0) | ((u32)f2bf(c1) << 16);
            }
        }
        __syncthreads();   // B2: hts/cts ready; hs/cs child rows now dead

        // ---- stage3: [embb|hts] @ WUc + gates; write parent h,c to hs,cs ---
        {
            int tok0 = tokLvl[lvb + min(l15, np - 1)];
            int tok1 = tokLvl[lvb + min(16 + l15, np - 1)];
            ffrag4 acc[2][12];
            #pragma unroll
            for (int i = 0; i < 2; ++i)
                #pragma unroll
                for (int j = 0; j < 12; ++j) acc[i][j] = (ffrag4)0.f;
            #pragma unroll 2
            for (int c = 0; c < 16; ++c) {
                bfrag8 a0, a1;
                if (c < 8) {
                    a0 = *(const bfrag8*)(embb + (size_t)tok0 * 256 + c * 32 + quad * 8);
                    a1 = *(const bfrag8*)(embb + (size_t)tok1 * 256 + c * 32 + quad * 8);
                } else {
                    a0 = *(const bfrag8*)&hts[l15][(c - 8) * 32 + quad * 8];
                    a1 = *(const bfrag8*)&hts[16 + l15][(c - 8) * 32 + quad * 8];
                }
                #pragma unroll
                for (int nt = 0; nt < 12; ++nt) {
                    bfrag8 b = *(const bfrag8*)(wuc + ((size_t)c * 768 + (nt >> 2) * 256 + w * 64 + (nt & 3) * 16 + l15) * 32 + quad * 8);
                    acc[0][nt] = __builtin_amdgcn_mfma_f32_16x16x32_bf16(a0, b, acc[0][nt], 0, 0, 0);
                    acc[1][nt] = __builtin_amdgcn_mfma_f32_16x16x32_bf16(a1, b, acc[1][nt], 0, 0, 0);
                }
            }
            #pragma unroll
            for (int st = 0; st < 4; ++st) {
                int hu = w * 64 + st * 16 + l15;
                float bi = loadv(biou, hu,       f_b);
                float bo = loadv(biou, 256 + hu, f_b);
                float bu = loadv(biou, 512 + hu, f_b);
                #pragma unroll
                for (int mt = 0; mt < 2; ++mt) {
                    #pragma unroll
                    for (int r = 0; r < 4; ++r) {
                        int p = mt * 16 + quad * 4 + r;
                        if (p < np) {
                            float iv = acc[mt][0 * 4 + st][r] + bi;
                            float ov = acc[mt][1 * 4 + st][r] + bo;
                            float uv = acc[mt][2 * 4 + st][r] + bu;
                            float cn = sigf(iv) * tanhf(uv) + bf2f(cts[p][hu]);
                            float hn = sigf(ov) * tanhf(cn);
                            hs[p][hu] = f2bf(hn);
                            cs[p][hu] = f2bf(cn);
                        }
                    }
                }
            }
        }
        __syncthreads();   // B3: end of level
    }

    // ---- final linear: out[g,:] = h_root @ lw^T + lb (h_root = hs row 0) ---
    if (t < NCLS) {
        float acc = 0.f;
        #pragma unroll 1
        for (int k = 0; k < 256; ++k)
            acc += loadv(lw, t * 256 + k, f_lw) * bf2f(hs[0][k]);
        out[(size_t)g * NCLS + t] = acc + loadv(lb, t, f_lw);
    }
}

__global__ void fill_kernel(float* out, int n, float v) {
    int i = blockIdx.x * 256 + threadIdx.x;
    if (i < n) out[i] = v;
}

// ============================ launcher =====================================
extern "C" void kernel_launch(void* const* d_in, const int* in_sizes, int n_in,
                              void* d_out, int out_size, void* d_ws, size_t ws_size,
                              hipStream_t stream)
{
    float* out = (float*)d_out;

    static const int exp_sizes[10] = {131040, 131040, 5120000, 196608, 196608,
                                      768, 65536, 256, 26624, 104};
    bool shapes_ok = (n_in == 10) && (out_size == B_G * NCLS);
    for (int i = 0; i < 10 && shapes_ok; ++i)
        if (in_sizes[i] != exp_sizes[i]) shapes_ok = false;
    if (!shapes_ok) {
        fill_kernel<<<(out_size + 255) / 256, 256, 0, stream>>>(out, out_size, 2.0f);
        return;
    }

    const int* x     = (const int*)d_in[0];
    const int* par   = (const int*)d_in[1];
    const void* emb  = d_in[2];
    const void* Wiou = d_in[3];
    const void* Uiou = d_in[4];
    const void* biou = d_in[5];
    const void* Ufw  = d_in[6];
    const void* Ufb  = d_in[7];
    const void* lw   = d_in[8];
    const void* lb   = d_in[9];

    // -------- workspace layout (byte offsets); total 152,453,184 B --------
    char* W = (char*)d_ws;
    u16* hA     = (u16*)(W + 0);              // bf16 [65536][256] odd levels
    u16* hB     = (u16*)(W + 33554432);       // bf16 [32768][256] even levels
    u16* cA     = (u16*)(W + 50331648);       // bf16 [65536][256] (fc in-place)
    u16* cB     = (u16*)(W + 83886080);       // bf16 [32768][256]
    u16* htild  = (u16*)(W + 100663296);      // bf16 [32768][256]
    u16* cagg   = (u16*)(W + 117440512);      // bf16 [32768][256]
    u16* WUc    = (u16*)(W + 134217728);      // bf16 [16][768][32]
    u16* Ufc    = (u16*)(W + 135004160);      // bf16 [8][256][32]
    int* tokLvl = (int*)(W + 135135232);      // int  [131072]
    int* cnt    = (int*)(W + 135659520);      // int  [65536]
    int* bucket = (int*)(W + 135921664);      // int  [65536*KCAP]
    u16* embb   = (u16*)(W + 142213120);      // bf16 [20000][256]
    int* flags  = (int*)(W + 152453120);      // int  [16]
    const size_t NEED = 152453184;            // <= 152,961,088 known-fit (r7)
    if (ws_size < NEED) {
        fill_kernel<<<(out_size + 255) / 256, 256, 0, stream>>>(out, out_size, 1.0f);
        return;
    }

    hipMemsetAsync(cnt, 0, 65536 * sizeof(int), stream);
    probe_kernel<<<1, 1, 0, stream>>>(emb, Wiou, Uiou, Ufw, lw, x, par, flags);
    prep_kernel<<<(NTOT + 255) / 256, 256, 0, stream>>>(x, par, tokLvl, cnt, bucket, flags);
    embconv_kernel<<<2500, 256, 0, stream>>>(emb, embb, flags);
    wuc_kernel<<<1536, 256, 0, stream>>>(Wiou, Uiou, WUc, flags);
    ufc_kernel<<<256, 256, 0, stream>>>(Ufw, Ufc, flags);

    // leaves d=11 (odd parity -> hA/cA), K=256
    gemm2_kernel<<<dim3(512, 4), 256, 0, stream>>>(
        8, 65536, tokLvl + LB(11), embb, WUc, biou,
        nullptr, nullptr, hA, cA, flags);

    for (int d = 10; d >= 6; --d) {
        const int cl = d + 1;
        const int NC = B_G << cl;
        const int NN = B_G << d;
        const u16* hch = (cl & 1) ? hA : hB;
        u16*       cch = (cl & 1) ? cA : cB;   // becomes fc in-place
        u16* hdst = (d & 1) ? hA : hB;
        u16* cdst = (d & 1) ? cA : cB;
        gemm1_kernel<<<NC / 64, 256, 0, stream>>>(hch, cch, Ufc, Ufb, flags);
        agg_kernel<<<(NN + 1) / 2, 256, 0, stream>>>(
            NN, (const u32*)hch, (const u32*)cch,
            cnt + LB(d), bucket + (size_t)LB(d) * KCAP,
            (u32*)htild, (u32*)cagg);
        gemm2_kernel<<<dim3((NN + 127) / 128, 4), 256, 0, stream>>>(
            16, NN, tokLvl + LB(d), embb, WUc, biou,
            htild, cagg, hdst, cdst, flags);
    }

    // levels d=5..0 + final linear: one block per graph, LDS-resident state
    tail_kernel<<<B_G, 256, 0, stream>>>(
        tokLvl, embb, WUc, biou, Ufc, Ufb,
        hB, cB, cnt, bucket, lw, lb, out, flags);
}

// Round 16
// 701.325 us; speedup vs baseline: 1.2595x; 1.0483x over previous
//
#include <hip/hip_runtime.h>
#include <hip/hip_bf16.h>

// DGL child-sum TreeLSTM, MFMA path, round 16 = round 15 with a 1024-thread
// (16-wave) tail. r15: tail 208us, spills gone (VGPR 160, WRITE 13KB), but
// only 4 waves/CU (1 block/CU due to 101KB LDS) -> latency-bound on L2
// weight streams (normalized VALU ~17%). Fix: 16 waves/block; each wave owns
// a 16-wide N-slice (stage1: 1 tile; stage3: 3 gates x 1 hu-tile, acc[2][3]),
// 4x memory-level parallelism, lower regs/wave, same traffic/LDS/barriers.
// Facts: inputs fp32 (probed), x/par int32, out fp32, ws >= 152,961,088 B.

#define B_G     32
#define NPG     4095
#define NTOT    (B_G * NPG)
#define NCLS    104
#define VOCAB   20000
#define PAD_TOK 19999
#define KCAP    24
#define LB(d)   (32 * ((1 << (d)) - 1))   // level base in level-major order

typedef unsigned short u16;
typedef unsigned int   u32;
typedef __attribute__((ext_vector_type(8))) short bfrag8;  // 8 bf16
typedef __attribute__((ext_vector_type(4))) float ffrag4;  // 4 f32

__device__ __forceinline__ float bf2f(u16 v) {
    union { u32 u; float f; } x; x.u = ((u32)v) << 16; return x.f;
}
__device__ __forceinline__ u16 f2bf(float f) {
    union { __hip_bfloat16 h; u16 u; } c; c.h = __float2bfloat16(f); return c.u;
}
__device__ __forceinline__ float loadv(const void* b, int i, int isf32) {
    return isf32 ? ((const float*)b)[i] : bf2f(((const u16*)b)[i]);
}
__device__ __forceinline__ float sigf(float x) { return 1.f / (1.f + __expf(-x)); }

// --------------------------- dtype probe -----------------------------------
__global__ void probe_kernel(const void* emb, const void* Wiou, const void* Uiou,
                             const void* Ufw, const void* lw,
                             const int* x32, const int* par32, int* flags)
{
    if (threadIdx.x != 0 || blockIdx.x != 0) return;
    const void* ptrs[5] = { emb, Wiou, Uiou, Ufw, lw };
    for (int i = 0; i < 5; ++i) {
        const u16* p = (const u16*)ptrs[i];
        int big = 0;
        for (int k = 0; k < 128; ++k) {
            u32 e = (((u32)p[k]) << 16 >> 23) & 0xFF;
            if (e >= 129) ++big;
        }
        flags[i] = (big >= 4) ? 1 : 0;     // 1 => fp32
    }
    int zx = 1;
    for (int k = 1; k <= 15; k += 2) if (x32[k] != 0) zx = 0;
    flags[5] = zx;                         // 1 => x int64
    flags[6] = (par32[3] == 0 && par32[5] == 0) ? 1 : 0;  // 1 => par int64
}

// ------------------- prep: tokens + per-parent child lists ------------------
__global__ __launch_bounds__(256) void prep_kernel(
    const int* __restrict__ x, const int* __restrict__ par,
    int* __restrict__ tokLvl, int* __restrict__ cnt, int* __restrict__ bucket,
    const int* __restrict__ flags)
{
    int gid = blockIdx.x * 256 + threadIdx.x;
    if (gid >= NTOT) return;
    int g     = (int)((u32)gid / NPG);
    int local = gid - g * NPG;
    int v  = local + 1;
    int d  = 31 - __clz(v);
    int j  = local - ((1 << d) - 1);
    int tok = flags[5] ? x[2 * gid] : x[gid];
    if (tok < 0 || tok >= VOCAB) tok = PAD_TOK;
    tokLvl[LB(d) + (g << d) + j] = tok;
    if (local > 0) {
        int p  = flags[6] ? par[2 * gid] : par[gid];
        p = max(0, min(p, NTOT - 1));
        int pg = (int)((u32)p / NPG);
        int pl = p - pg * NPG;
        int pd = d - 1;
        int ps = LB(pd) + (pg << pd) + (pl - ((1 << pd) - 1));
        ps = max(0, min(ps, 65503));
        int slot = atomicAdd(&cnt[ps], 1);
        if (slot < KCAP) bucket[(size_t)ps * KCAP + slot] = (g << d) + j;
    }
}

// emb -> bf16 table, PAD row zeroed
__global__ __launch_bounds__(256) void embconv_kernel(
    const void* __restrict__ emb, u16* __restrict__ embb,
    const int* __restrict__ flags)
{
    int i8 = (blockIdx.x * 256 + threadIdx.x) * 8;
    if (i8 >= VOCAB * 256) return;
    u16 v[8];
    if ((i8 >> 8) == PAD_TOK) {
        #pragma unroll
        for (int s = 0; s < 8; ++s) v[s] = 0;
    } else if (flags[0]) {
        const float* e = (const float*)emb + i8;
        float4 a = *(const float4*)e;
        float4 b = *(const float4*)(e + 4);
        v[0]=f2bf(a.x); v[1]=f2bf(a.y); v[2]=f2bf(a.z); v[3]=f2bf(a.w);
        v[4]=f2bf(b.x); v[5]=f2bf(b.y); v[6]=f2bf(b.z); v[7]=f2bf(b.w);
    } else {
        *(uint4*)v = *(const uint4*)((const u16*)emb + i8);
    }
    *(uint4*)(embb + i8) = *(uint4*)v;
}

// combined [Wiou|Uiou] -> bf16, K-chunked wuc[c][768][32], c=0..15
__global__ __launch_bounds__(256) void wuc_kernel(
    const void* __restrict__ Wiou, const void* __restrict__ Uiou,
    u16* __restrict__ wuc, const int* __restrict__ flags)
{
    int idx = blockIdx.x * 256 + threadIdx.x;
    if (idx >= 16 * 768 * 32) return;
    int c   = idx / 24576;
    int rem = idx - c * 24576;
    int out = rem >> 5;
    int kk  = rem & 31;
    int k   = c * 32 + kk;
    float v = (k < 256) ? loadv(Wiou, out * 256 + k, flags[1])
                        : loadv(Uiou, out * 256 + (k - 256), flags[2]);
    wuc[idx] = f2bf(v);
}

// Ufw -> bf16, chunked ufc[c][256][32], c=0..7
__global__ __launch_bounds__(256) void ufc_kernel(
    const void* __restrict__ Ufw, u16* __restrict__ ufc,
    const int* __restrict__ flags)
{
    int idx = blockIdx.x * 256 + threadIdx.x;
    if (idx >= 8 * 256 * 32) return;
    int c   = idx >> 13;
    int rem = idx & 8191;
    int out = rem >> 5;
    int kk  = rem & 31;
    ufc[idx] = f2bf(loadv(Ufw, out * 256 + c * 32 + kk, flags[3]));
}

// GEMM1: fc = sigmoid(h_ch @ Ufw^T + b) * c_ch, IN-PLACE over cbuf. M=64.
__global__ __launch_bounds__(256, 3) void gemm1_kernel(
    const u16* __restrict__ hch, u16* cbuf,
    const u16* __restrict__ ufc, const void* __restrict__ ufb,
    const int* __restrict__ flags)
{
    __shared__ u16 As[64][40];
    __shared__ u16 Bs[256][40];
    const int t = threadIdx.x;
    const int w = t >> 6, lane = t & 63, quad = lane >> 4, l15 = lane & 15;
    const int m0 = blockIdx.x * 64;
    const int f_uf = flags[3];

    ffrag4 acc[4][4];
    #pragma unroll
    for (int i = 0; i < 4; ++i)
        #pragma unroll
        for (int j = 0; j < 4; ++j) acc[i][j] = (ffrag4)0.f;

    const int arow = t >> 2, aseg = t & 3;
    for (int c = 0; c < 8; ++c) {
        *(uint4*)&As[arow][aseg * 8] =
            *(const uint4*)(hch + (size_t)(m0 + arow) * 256 + c * 32 + aseg * 8);
        #pragma unroll
        for (int r16 = 0; r16 < 4; ++r16) {
            int row = r16 * 64 + arow;
            *(uint4*)&Bs[row][aseg * 8] =
                *(const uint4*)(ufc + ((size_t)c * 256 + row) * 32 + aseg * 8);
        }
        __syncthreads();
        bfrag8 a[4], b[4];
        #pragma unroll
        for (int mt = 0; mt < 4; ++mt) a[mt] = *(bfrag8*)&As[mt * 16 + l15][quad * 8];
        #pragma unroll
        for (int nt = 0; nt < 4; ++nt) b[nt] = *(bfrag8*)&Bs[w * 64 + nt * 16 + l15][quad * 8];
        #pragma unroll
        for (int mt = 0; mt < 4; ++mt)
            #pragma unroll
            for (int nt = 0; nt < 4; ++nt)
                acc[mt][nt] = __builtin_amdgcn_mfma_f32_16x16x32_bf16(a[mt], b[nt], acc[mt][nt], 0, 0, 0);
        __syncthreads();
    }

    #pragma unroll
    for (int nt = 0; nt < 4; ++nt) {
        int hu = w * 64 + nt * 16 + l15;
        float fb = loadv(ufb, hu, f_uf);
        #pragma unroll
        for (int mt = 0; mt < 4; ++mt) {
            #pragma unroll
            for (int r = 0; r < 4; ++r) {
                int node = m0 + mt * 16 + quad * 4 + r;
                size_t off = (size_t)node * 256 + hu;
                float f = sigf(acc[mt][nt][r] + fb);
                cbuf[off] = f2bf(f * bf2f(cbuf[off]));
            }
        }
    }
}

// agg: htild[p] = sum h_child, cagg[p] = sum fc_child. Coalesced.
__global__ __launch_bounds__(256) void agg_kernel(
    int NN, const u32* __restrict__ hch32, const u32* __restrict__ fcch32,
    const int* __restrict__ cnt_d, const int* __restrict__ bucket_d,
    u32* __restrict__ htild32, u32* __restrict__ cagg32)
{
    int pi  = blockIdx.x * 2 + (threadIdx.x >> 7);
    int col = threadIdx.x & 127;
    if (pi >= NN) return;
    int nc = min(cnt_d[pi], KCAP);
    float h0 = 0.f, h1 = 0.f, c0 = 0.f, c1 = 0.f;
    for (int ci = 0; ci < nc; ++ci) {
        int ch = bucket_d[(size_t)pi * KCAP + ci];
        u32 hv = hch32[(size_t)ch * 128 + col];
        u32 fv = fcch32[(size_t)ch * 128 + col];
        h0 += bf2f((u16)(hv & 0xffff)); h1 += bf2f((u16)(hv >> 16));
        c0 += bf2f((u16)(fv & 0xffff)); c1 += bf2f((u16)(fv >> 16));
    }
    htild32[(size_t)pi * 128 + col] = (u32)f2bf(h0) | ((u32)f2bf(h1) << 16);
    cagg32[(size_t)pi * 128 + col]  = (u32)f2bf(c0) | ((u32)f2bf(c1) << 16);
}

// GEMM2: IOU = [embb[x] | Htild] @ [Wiou|Uiou]^T + gates. M=128, N=192/block.
__global__ __launch_bounds__(256, 3) void gemm2_kernel(
    int nchunk, int NN,
    const int* __restrict__ tokLvl_d, const u16* __restrict__ embb,
    const u16* __restrict__ wuc, const void* __restrict__ biou,
    const u16* __restrict__ htild, const u16* __restrict__ cagg,
    u16* __restrict__ hdst, u16* __restrict__ cdst,
    const int* __restrict__ flags)
{
    __shared__ u16 As[128][40];
    __shared__ u16 Bs[192][40];
    __shared__ int toks[128];
    const int t = threadIdx.x;
    const int w = t >> 6, lane = t & 63, quad = lane >> 4, l15 = lane & 15;
    const int m0 = blockIdx.x * 128;
    const int q  = blockIdx.y;
    const int f_b = flags[1];

    if (t < 128) toks[t] = tokLvl_d[m0 + t];
    __syncthreads();

    ffrag4 acc[8][3];
    #pragma unroll
    for (int i = 0; i < 8; ++i)
        #pragma unroll
        for (int j = 0; j < 3; ++j) acc[i][j] = (ffrag4)0.f;

    const int arow = t >> 1, ac0 = (t & 1) * 16;
    const int brow = t >> 2, bseg = t & 3;
    for (int c = 0; c < nchunk; ++c) {
        if (c < 8) {
            const u16* e = embb + (size_t)toks[arow] * 256 + c * 32 + ac0;
            *(uint4*)&As[arow][ac0]     = *(const uint4*)e;
            *(uint4*)&As[arow][ac0 + 8] = *(const uint4*)(e + 8);
        } else {
            const u16* hsrc = htild + (size_t)(m0 + arow) * 256 + (c - 8) * 32 + ac0;
            *(uint4*)&As[arow][ac0]     = *(const uint4*)hsrc;
            *(uint4*)&As[arow][ac0 + 8] = *(const uint4*)(hsrc + 8);
        }
        #pragma unroll
        for (int g = 0; g < 3; ++g) {
            *(uint4*)&Bs[g * 64 + brow][bseg * 8] =
                *(const uint4*)(wuc + ((size_t)c * 768 + g * 256 + q * 64 + brow) * 32 + bseg * 8);
        }
        __syncthreads();
        bfrag8 a[8], b[3];
        #pragma unroll
        for (int mt = 0; mt < 8; ++mt) a[mt] = *(bfrag8*)&As[mt * 16 + l15][quad * 8];
        #pragma unroll
        for (int g = 0; g < 3; ++g) b[g] = *(bfrag8*)&Bs[g * 64 + w * 16 + l15][quad * 8];
        #pragma unroll
        for (int mt = 0; mt < 8; ++mt)
            #pragma unroll
            for (int g = 0; g < 3; ++g)
                acc[mt][g] = __builtin_amdgcn_mfma_f32_16x16x32_bf16(a[mt], b[g], acc[mt][g], 0, 0, 0);
        __syncthreads();
    }

    const int hu = q * 64 + w * 16 + l15;
    const float bi = loadv(biou, hu,       f_b);
    const float bo = loadv(biou, 256 + hu, f_b);
    const float bu = loadv(biou, 512 + hu, f_b);
    #pragma unroll
    for (int mt = 0; mt < 8; ++mt) {
        #pragma unroll
        for (int r = 0; r < 4; ++r) {
            int node = m0 + mt * 16 + quad * 4 + r;
            if (node < NN) {
                size_t off = (size_t)node * 256 + hu;
                float iv = acc[mt][0][r] + bi;
                float ov = acc[mt][1][r] + bo;
                float uv = acc[mt][2][r] + bu;
                float cg = cagg ? bf2f(cagg[off]) : 0.f;
                float cn = sigf(iv) * tanhf(uv) + cg;
                float hn = sigf(ov) * tanhf(cn);
                hdst[off] = f2bf(hn);
                cdst[off] = f2bf(cn);
            }
        }
    }
}

// tail: levels d=5..0 + final linear; one 1024-thread block/graph (16 waves);
// ALL state in LDS; per-wave N-slice = 16 outputs -> low regs, high MLP.
__global__ __launch_bounds__(1024, 1) void tail_kernel(
    const int* __restrict__ tokLvl, const u16* __restrict__ embb,
    const u16* __restrict__ wuc, const void* __restrict__ biou,
    const u16* __restrict__ ufc, const void* __restrict__ ufb,
    const u16* __restrict__ hB, const u16* __restrict__ cB,
    const int* __restrict__ cnt, const int* __restrict__ bucket,
    const void* __restrict__ lw, const void* __restrict__ lb,
    float* __restrict__ out, const int* __restrict__ flags)
{
    __shared__ u16 hs[64][264];    // child h; parent h overwrites rows < np
    __shared__ u16 cs[64][264];    // child c -> fc (stage1) -> parent c
    __shared__ u16 hts[32][264];   // htild
    __shared__ u16 cts[32][264];   // cagg
    const int t = threadIdx.x;     // 0..1023
    const int g = blockIdx.x;
    const int w = t >> 6;          // wave 0..15
    const int lane = t & 63, quad = lane >> 4, l15 = lane & 15;
    const int f_uf = flags[3], f_b = flags[1], f_lw = flags[4];

    // preload child h,c of d=5 (level 6: 64 rows/graph)
    #pragma unroll 1
    for (int i = t; i < 64 * 32; i += 1024) {
        int j = i >> 5, seg = i & 31;
        size_t off = (((size_t)((g << 6) + j)) << 8) + seg * 8;
        *(uint4*)&hs[j][seg * 8] = *(const uint4*)(hB + off);
        *(uint4*)&cs[j][seg * 8] = *(const uint4*)(cB + off);
    }
    __syncthreads();

    #pragma unroll 1
    for (int d = 5; d >= 0; --d) {
        const int ncr = 1 << (d + 1);
        const int np  = 1 << d;
        const int lvb = LB(d) + (g << d);
        const int hu  = w * 16 + l15;   // this wave's output slice (16 wide)

        // ---- stage1: cs[j] <- sig(hs[j]@Ufw^T + b) * cs[j]; wave w owns
        //      outputs [w*16, w*16+16). M=64 (4 m-tiles).
        {
            ffrag4 facc[4];
            #pragma unroll
            for (int i = 0; i < 4; ++i) facc[i] = (ffrag4)0.f;
            #pragma unroll 2
            for (int c = 0; c < 8; ++c) {
                bfrag8 a[4];
                #pragma unroll
                for (int mt = 0; mt < 4; ++mt)
                    a[mt] = *(const bfrag8*)&hs[mt * 16 + l15][c * 32 + quad * 8];
                bfrag8 b = *(const bfrag8*)(ufc + ((size_t)c * 256 + w * 16 + l15) * 32 + quad * 8);
                #pragma unroll
                for (int mt = 0; mt < 4; ++mt)
                    facc[mt] = __builtin_amdgcn_mfma_f32_16x16x32_bf16(a[mt], b, facc[mt], 0, 0, 0);
            }
            float fb = loadv(ufb, hu, f_uf);
            #pragma unroll
            for (int mt = 0; mt < 4; ++mt) {
                #pragma unroll
                for (int r = 0; r < 4; ++r) {
                    int j = mt * 16 + quad * 4 + r;
                    if (j < ncr) {
                        float f = sigf(facc[mt][r] + fb);
                        cs[j][hu] = f2bf(f * bf2f(cs[j][hu]));
                    }
                }
            }
        }
        __syncthreads();   // B1: fc visible; hs still child h

        // ---- stage2: gather htild (hs) + cagg (cs) per parent --------------
        {
            const int col = t & 127;
            #pragma unroll 1
            for (int pi = t >> 7; pi < np; pi += 8) {
                int nc = min(cnt[lvb + pi], KCAP);
                const int* bk = bucket + (size_t)(lvb + pi) * KCAP;
                float h0 = 0.f, h1 = 0.f, c0 = 0.f, c1 = 0.f;
                #pragma unroll 1
                for (int ci = 0; ci < nc; ++ci) {
                    int j = bk[ci] & (ncr - 1);
                    u32 hv = *(const u32*)&hs[j][col * 2];
                    u32 cv = *(const u32*)&cs[j][col * 2];
                    h0 += bf2f((u16)(hv & 0xffff)); h1 += bf2f((u16)(hv >> 16));
                    c0 += bf2f((u16)(cv & 0xffff)); c1 += bf2f((u16)(cv >> 16));
                }
                *(u32*)&hts[pi][col * 2] = (u32)f2bf(h0) | ((u32)f2bf(h1) << 16);
                *(u32*)&cts[pi][col * 2] = (u32)f2bf(c0) | ((u32)f2bf(c1) << 16);
            }
        }
        __syncthreads();   // B2: hts/cts ready; hs/cs child rows now dead

        // ---- stage3: [embb|hts] @ WUc + gates; wave w owns hu-tile w of 256
        //      for ALL 3 gates (N-rows g3*256 + w*16). M=32 (2 m-tiles).
        {
            int tok0 = tokLvl[lvb + min(l15, np - 1)];
            int tok1 = tokLvl[lvb + min(16 + l15, np - 1)];
            ffrag4 acc[2][3];
            #pragma unroll
            for (int i = 0; i < 2; ++i)
                #pragma unroll
                for (int j = 0; j < 3; ++j) acc[i][j] = (ffrag4)0.f;
            #pragma unroll 2
            for (int c = 0; c < 16; ++c) {
                bfrag8 a0, a1;
                if (c < 8) {
                    a0 = *(const bfrag8*)(embb + (size_t)tok0 * 256 + c * 32 + quad * 8);
                    a1 = *(const bfrag8*)(embb + (size_t)tok1 * 256 + c * 32 + quad * 8);
                } else {
                    a0 = *(const bfrag8*)&hts[l15][(c - 8) * 32 + quad * 8];
                    a1 = *(const bfrag8*)&hts[16 + l15][(c - 8) * 32 + quad * 8];
                }
                #pragma unroll
                for (int g3 = 0; g3 < 3; ++g3) {
                    bfrag8 b = *(const bfrag8*)(wuc + ((size_t)c * 768 + g3 * 256 + w * 16 + l15) * 32 + quad * 8);
                    acc[0][g3] = __builtin_amdgcn_mfma_f32_16x16x32_bf16(a0, b, acc[0][g3], 0, 0, 0);
                    acc[1][g3] = __builtin_amdgcn_mfma_f32_16x16x32_bf16(a1, b, acc[1][g3], 0, 0, 0);
                }
            }
            float bi = loadv(biou, hu,       f_b);
            float bo = loadv(biou, 256 + hu, f_b);
            float bu = loadv(biou, 512 + hu, f_b);
            #pragma unroll
            for (int mt = 0; mt < 2; ++mt) {
                #pragma unroll
                for (int r = 0; r < 4; ++r) {
                    int p = mt * 16 + quad * 4 + r;
                    if (p < np) {
                        float iv = acc[mt][0][r] + bi;
                        float ov = acc[mt][1][r] + bo;
                        float uv = acc[mt][2][r] + bu;
                        float cn = sigf(iv) * tanhf(uv) + bf2f(cts[p][hu]);
                        float hn = sigf(ov) * tanhf(cn);
                        hs[p][hu] = f2bf(hn);
                        cs[p][hu] = f2bf(cn);
                    }
                }
            }
        }
        __syncthreads();   // B3: end of level
    }

    // ---- final linear: out[g,:] = h_root @ lw^T + lb (h_root = hs row 0) ---
    if (t < NCLS) {
        float acc = 0.f;
        #pragma unroll 1
        for (int k = 0; k < 256; ++k)
            acc += loadv(lw, t * 256 + k, f_lw) * bf2f(hs[0][k]);
        out[(size_t)g * NCLS + t] = acc + loadv(lb, t, f_lw);
    }
}

__global__ void fill_kernel(float* out, int n, float v) {
    int i = blockIdx.x * 256 + threadIdx.x;
    if (i < n) out[i] = v;
}

// ============================ launcher =====================================
extern "C" void kernel_launch(void* const* d_in, const int* in_sizes, int n_in,
                              void* d_out, int out_size, void* d_ws, size_t ws_size,
                              hipStream_t stream)
{
    float* out = (float*)d_out;

    static const int exp_sizes[10] = {131040, 131040, 5120000, 196608, 196608,
                                      768, 65536, 256, 26624, 104};
    bool shapes_ok = (n_in == 10) && (out_size == B_G * NCLS);
    for (int i = 0; i < 10 && shapes_ok; ++i)
        if (in_sizes[i] != exp_sizes[i]) shapes_ok = false;
    if (!shapes_ok) {
        fill_kernel<<<(out_size + 255) / 256, 256, 0, stream>>>(out, out_size, 2.0f);
        return;
    }

    const int* x     = (const int*)d_in[0];
    const int* par   = (const int*)d_in[1];
    const void* emb  = d_in[2];
    const void* Wiou = d_in[3];
    const void* Uiou = d_in[4];
    const void* biou = d_in[5];
    const void* Ufw  = d_in[6];
    const void* Ufb  = d_in[7];
    const void* lw   = d_in[8];
    const void* lb   = d_in[9];

    // -------- workspace layout (byte offsets); total 152,453,184 B --------
    char* W = (char*)d_ws;
    u16* hA     = (u16*)(W + 0);              // bf16 [65536][256] odd levels
    u16* hB     = (u16*)(W + 33554432);       // bf16 [32768][256] even levels
    u16* cA     = (u16*)(W + 50331648);       // bf16 [65536][256] (fc in-place)
    u16* cB     = (u16*)(W + 83886080);       // bf16 [32768][256]
    u16* htild  = (u16*)(W + 100663296);      // bf16 [32768][256]
    u16* cagg   = (u16*)(W + 117440512);      // bf16 [32768][256]
    u16* WUc    = (u16*)(W + 134217728);      // bf16 [16][768][32]
    u16* Ufc    = (u16*)(W + 135004160);      // bf16 [8][256][32]
    int* tokLvl = (int*)(W + 135135232);      // int  [131072]
    int* cnt    = (int*)(W + 135659520);      // int  [65536]
    int* bucket = (int*)(W + 135921664);      // int  [65536*KCAP]
    u16* embb   = (u16*)(W + 142213120);      // bf16 [20000][256]
    int* flags  = (int*)(W + 152453120);      // int  [16]
    const size_t NEED = 152453184;            // <= 152,961,088 known-fit (r7)
    if (ws_size < NEED) {
        fill_kernel<<<(out_size + 255) / 256, 256, 0, stream>>>(out, out_size, 1.0f);
        return;
    }

    hipMemsetAsync(cnt, 0, 65536 * sizeof(int), stream);
    probe_kernel<<<1, 1, 0, stream>>>(emb, Wiou, Uiou, Ufw, lw, x, par, flags);
    prep_kernel<<<(NTOT + 255) / 256, 256, 0, stream>>>(x, par, tokLvl, cnt, bucket, flags);
    embconv_kernel<<<2500, 256, 0, stream>>>(emb, embb, flags);
    wuc_kernel<<<1536, 256, 0, stream>>>(Wiou, Uiou, WUc, flags);
    ufc_kernel<<<256, 256, 0, stream>>>(Ufw, Ufc, flags);

    // leaves d=11 (odd parity -> hA/cA), K=256
    gemm2_kernel<<<dim3(512, 4), 256, 0, stream>>>(
        8, 65536, tokLvl + LB(11), embb, WUc, biou,
        nullptr, nullptr, hA, cA, flags);

    for (int d = 10; d >= 6; --d) {
        const int cl = d + 1;
        const int NC = B_G << cl;
        const int NN = B_G << d;
        const u16* hch = (cl & 1) ? hA : hB;
        u16*       cch = (cl & 1) ? cA : cB;   // becomes fc in-place
        u16* hdst = (d & 1) ? hA : hB;
        u16* cdst = (d & 1) ? cA : cB;
        gemm1_kernel<<<NC / 64, 256, 0, stream>>>(hch, cch, Ufc, Ufb, flags);
        agg_kernel<<<(NN + 1) / 2, 256, 0, stream>>>(
            NN, (const u32*)hch, (const u32*)cch,
            cnt + LB(d), bucket + (size_t)LB(d) * KCAP,
            (u32*)htild, (u32*)cagg);
        gemm2_kernel<<<dim3((NN + 127) / 128, 4), 256, 0, stream>>>(
            16, NN, tokLvl + LB(d), embb, WUc, biou,
            htild, cagg, hdst, cdst, flags);
    }

    // levels d=5..0 + final linear: one 1024-thread block/graph, LDS-resident
    tail_kernel<<<B_G, 1024, 0, stream>>>(
        tokLvl, embb, WUc, biou, Ufc, Ufb,
        hB, cB, cnt, bucket, lw, lb, out, flags);
}